// Round 1
// baseline (1385.397 us; speedup 1.0000x reference)
//
#include <hip/hip_runtime.h>
#include <cstddef>

constexpr int NB = 16;   // batch
constexpr int NP = 512;  // pieces
constexpr int ND = 1024; // dim
constexpr int NW = 400;  // words
constexpr int NT = 32;   // triggers
constexpr int NE = 64;   // entities
constexpr int NH = 600;  // hidden

// ---------------------------------------------------------------------------
// Kernel 1: word means over piece intervals. grid = NB*NW, block = 256.
__global__ __launch_bounds__(256) void word_mean_kernel(
    const float* __restrict__ piece, const int* __restrict__ widx,
    float* __restrict__ word) {
    int bw = blockIdx.x;           // b*NW + w
    int b = bw / NW;
    int s = widx[bw * 2], e = widx[bw * 2 + 1];
    int col = threadIdx.x * 4;
    const float* base = piece + (size_t)b * NP * ND + col;
    float4 acc = make_float4(0.f, 0.f, 0.f, 0.f);
    for (int r = s; r < e; ++r) {
        float4 v = *(const float4*)(base + (size_t)r * ND);
        acc.x += v.x; acc.y += v.y; acc.z += v.z; acc.w += v.w;
    }
    float inv = 1.0f / (float)(e - s);
    acc.x *= inv; acc.y *= inv; acc.z *= inv; acc.w *= inv;
    *(float4*)(word + (size_t)bw * ND + col) = acc;
}

// ---------------------------------------------------------------------------
// Kernel 2: span means over word intervals (trig + ent in one grid).
// grid = NB*(NT+NE), block = 256.
__global__ __launch_bounds__(256) void span_mean_kernel(
    const float* __restrict__ word, const int* __restrict__ tidx,
    const int* __restrict__ eidx, float* __restrict__ trig,
    float* __restrict__ ent) {
    int id = blockIdx.x;
    const int* idx;
    float* out;
    int b;
    if (id < NB * NT) {
        b = id / NT; idx = tidx + id * 2; out = trig + (size_t)id * ND;
    } else {
        int id2 = id - NB * NT;
        b = id2 / NE; idx = eidx + id2 * 2; out = ent + (size_t)id2 * ND;
    }
    int s = idx[0], e = idx[1];
    int col = threadIdx.x * 4;
    const float* base = word + (size_t)b * NW * ND + col;
    float4 acc = make_float4(0.f, 0.f, 0.f, 0.f);
    for (int r = s; r < e; ++r) {
        float4 v = *(const float4*)(base + (size_t)r * ND);
        acc.x += v.x; acc.y += v.y; acc.z += v.z; acc.w += v.w;
    }
    float inv = 1.0f / (float)(e - s);
    acc.x *= inv; acc.y *= inv; acc.z *= inv; acc.w *= inv;
    *(float4*)(out + col) = acc;
}

// ---------------------------------------------------------------------------
// Kernel 3: pre-projection GEMM. C[M][NH] = A[M][ND] @ W0[rowbase:rowbase+ND][NH]
// Tile 64x64x32, block (16,16), 4x4 per thread.
__global__ __launch_bounds__(256) void pre_gemm_kernel(
    const float* __restrict__ A, const float* __restrict__ W0, int rowbase,
    float* __restrict__ C) {
    __shared__ float As[64][36];   // stride 36: float4-aligned, 2-way bank (free)
    __shared__ float Ws[32][64];
    int tx = threadIdx.x, ty = threadIdx.y;
    int tid = ty * 16 + tx;
    int mBase = blockIdx.x * 64;
    int nBase = blockIdx.y * 64;
    bool nFull = (nBase + 63) < NH;
    float acc[4][4] = {};
    int am = tid >> 2, ak0 = (tid & 3) * 8;
    int wk = tid >> 3, wn0 = (tid & 7) * 8;
    const float* arow = A + (size_t)(mBase + am) * ND;

    for (int kb = 0; kb < ND; kb += 32) {
        __syncthreads();
        {
            const float* src = arow + kb + ak0;
            float4 v0 = *(const float4*)(src);
            float4 v1 = *(const float4*)(src + 4);
            *(float4*)&As[am][ak0] = v0;
            *(float4*)&As[am][ak0 + 4] = v1;
        }
        {
            const float* src = W0 + (size_t)(rowbase + kb + wk) * NH + nBase + wn0;
            if (nFull) {
                float4 v0 = *(const float4*)(src);
                float4 v1 = *(const float4*)(src + 4);
                *(float4*)&Ws[wk][wn0] = v0;
                *(float4*)&Ws[wk][wn0 + 4] = v1;
            } else {
                for (int j = 0; j < 8; ++j) {
                    int n = nBase + wn0 + j;
                    Ws[wk][wn0 + j] = (n < NH) ? src[j] : 0.0f;
                }
            }
        }
        __syncthreads();
#pragma unroll
        for (int kk = 0; kk < 32; ++kk) {
            float a0 = As[ty * 4 + 0][kk];
            float a1 = As[ty * 4 + 1][kk];
            float a2 = As[ty * 4 + 2][kk];
            float a3 = As[ty * 4 + 3][kk];
            float4 bv = *(const float4*)&Ws[kk][tx * 4];
            acc[0][0] += a0 * bv.x; acc[0][1] += a0 * bv.y; acc[0][2] += a0 * bv.z; acc[0][3] += a0 * bv.w;
            acc[1][0] += a1 * bv.x; acc[1][1] += a1 * bv.y; acc[1][2] += a1 * bv.z; acc[1][3] += a1 * bv.w;
            acc[2][0] += a2 * bv.x; acc[2][1] += a2 * bv.y; acc[2][2] += a2 * bv.z; acc[2][3] += a2 * bv.w;
            acc[3][0] += a3 * bv.x; acc[3][1] += a3 * bv.y; acc[3][2] += a3 * bv.z; acc[3][3] += a3 * bv.w;
        }
    }
#pragma unroll
    for (int i = 0; i < 4; ++i)
#pragma unroll
        for (int j = 0; j < 4; ++j) {
            int n = nBase + tx * 4 + j;
            if (n < NH) C[(size_t)(mBase + ty * 4 + i) * NH + n] = acc[i][j];
        }
}

// ---------------------------------------------------------------------------
// Kernel 4: pairwise GEMM + fused FFN epilogue.
// Block = (b,t, n-chunk). M-dim = 64 entities, N = 64 hidden cols, K = 2048
// (first 1024: t*e vs W0c; second 1024: |t-e| vs W0d).
__global__ __launch_bounds__(256) void pair_ffn_kernel(
    const float* __restrict__ trig,   // [NB*NT][ND]
    const float* __restrict__ ent,    // [NB*NE][ND]
    const float* __restrict__ W0,     // [4*ND][NH]
    const float* __restrict__ b0,     // [NH]
    const float* __restrict__ pre_t,  // [NB*NT][NH]
    const float* __restrict__ pre_e,  // [NB*NE][NH]
    const float* __restrict__ W1,     // [NH][2]
    const float* __restrict__ b1,     // [2]
    float* __restrict__ out) {        // [NB*NT*NE][2], pre-zeroed
    __shared__ float Xs[64][36];
    __shared__ float Ws[32][64];
    int tx = threadIdx.x, ty = threadIdx.y;
    int tid = ty * 16 + tx;
    int bt = blockIdx.x;          // b*NT + t
    int b = bt / NT;
    int nBase = blockIdx.y * 64;
    bool nFull = (nBase + 63) < NH;
    float acc[4][4] = {};
    int xe = tid >> 2, xk0 = (tid & 3) * 8;
    int wk = tid >> 3, wn0 = (tid & 7) * 8;
    const float* trow = trig + (size_t)bt * ND;
    const float* erow = ent + (size_t)(b * NE + xe) * ND;

    for (int kb = 0; kb < 2 * ND; kb += 32) {
        __syncthreads();
        {
            int k = kb + xk0;
            int kr = k & (ND - 1);
            float4 t0 = *(const float4*)(trow + kr);
            float4 t1 = *(const float4*)(trow + kr + 4);
            float4 e0 = *(const float4*)(erow + kr);
            float4 e1 = *(const float4*)(erow + kr + 4);
            float4 x0, x1;
            if (kb < ND) {   // uniform per tile (1024 % 32 == 0)
                x0 = make_float4(t0.x * e0.x, t0.y * e0.y, t0.z * e0.z, t0.w * e0.w);
                x1 = make_float4(t1.x * e1.x, t1.y * e1.y, t1.z * e1.z, t1.w * e1.w);
            } else {
                x0 = make_float4(fabsf(t0.x - e0.x), fabsf(t0.y - e0.y),
                                 fabsf(t0.z - e0.z), fabsf(t0.w - e0.w));
                x1 = make_float4(fabsf(t1.x - e1.x), fabsf(t1.y - e1.y),
                                 fabsf(t1.z - e1.z), fabsf(t1.w - e1.w));
            }
            *(float4*)&Xs[xe][xk0] = x0;
            *(float4*)&Xs[xe][xk0 + 4] = x1;
        }
        {
            // W0 rows 2*ND + kb + wk  (covers W0c then W0d contiguously)
            const float* src = W0 + (size_t)(2 * ND + kb + wk) * NH + nBase + wn0;
            if (nFull) {
                float4 v0 = *(const float4*)(src);
                float4 v1 = *(const float4*)(src + 4);
                *(float4*)&Ws[wk][wn0] = v0;
                *(float4*)&Ws[wk][wn0 + 4] = v1;
            } else {
                for (int j = 0; j < 8; ++j) {
                    int n = nBase + wn0 + j;
                    Ws[wk][wn0 + j] = (n < NH) ? src[j] : 0.0f;
                }
            }
        }
        __syncthreads();
#pragma unroll
        for (int kk = 0; kk < 32; ++kk) {
            float a0 = Xs[ty * 4 + 0][kk];
            float a1 = Xs[ty * 4 + 1][kk];
            float a2 = Xs[ty * 4 + 2][kk];
            float a3 = Xs[ty * 4 + 3][kk];
            float4 bv = *(const float4*)&Ws[kk][tx * 4];
            acc[0][0] += a0 * bv.x; acc[0][1] += a0 * bv.y; acc[0][2] += a0 * bv.z; acc[0][3] += a0 * bv.w;
            acc[1][0] += a1 * bv.x; acc[1][1] += a1 * bv.y; acc[1][2] += a1 * bv.z; acc[1][3] += a1 * bv.w;
            acc[2][0] += a2 * bv.x; acc[2][1] += a2 * bv.y; acc[2][2] += a2 * bv.z; acc[2][3] += a2 * bv.w;
            acc[3][0] += a3 * bv.x; acc[3][1] += a3 * bv.y; acc[3][2] += a3 * bv.z; acc[3][3] += a3 * bv.w;
        }
    }

    // Epilogue: h = relu(acc + pre_t + pre_e + b0); out += h @ W1 (+ b1 once).
    const float* preT = pre_t + (size_t)bt * NH;
    int n0 = nBase + tx * 4;
    float b0v[4], w10[4], w11[4], ptv[4];
#pragma unroll
    for (int j = 0; j < 4; ++j) {
        int n = n0 + j;
        bool v = n < NH;
        b0v[j] = v ? b0[n] : 0.0f;
        w10[j] = v ? W1[n * 2 + 0] : 0.0f;
        w11[j] = v ? W1[n * 2 + 1] : 0.0f;
        ptv[j] = v ? preT[n] : 0.0f;
    }
#pragma unroll
    for (int i = 0; i < 4; ++i) {
        int e = ty * 4 + i;
        const float* preE = pre_e + (size_t)(b * NE + e) * NH;
        float s0 = 0.f, s1 = 0.f;
#pragma unroll
        for (int j = 0; j < 4; ++j) {
            int n = n0 + j;
            if (n < NH) {
                float h = acc[i][j] + ptv[j] + preE[n] + b0v[j];
                h = fmaxf(h, 0.0f);
                s0 += h * w10[j];
                s1 += h * w11[j];
            }
        }
        // reduce across the 16 tx lanes (contiguous within the wave)
        for (int m = 8; m >= 1; m >>= 1) {
            s0 += __shfl_xor(s0, m);
            s1 += __shfl_xor(s1, m);
        }
        if (tx == 0) {
            size_t o = ((size_t)bt * NE + e) * 2;
            if (blockIdx.y == 0) { s0 += b1[0]; s1 += b1[1]; }
            atomicAdd(out + o, s0);
            atomicAdd(out + o + 1, s1);
        }
    }
}

// ---------------------------------------------------------------------------
extern "C" void kernel_launch(void* const* d_in, const int* in_sizes, int n_in,
                              void* d_out, int out_size, void* d_ws,
                              size_t ws_size, hipStream_t stream) {
    const float* piece = (const float*)d_in[0];
    const int* widx = (const int*)d_in[1];
    const int* tidx = (const int*)d_in[2];
    const int* eidx = (const int*)d_in[3];
    const float* W0 = (const float*)d_in[4];
    const float* b0 = (const float*)d_in[5];
    const float* W1 = (const float*)d_in[6];
    const float* b1 = (const float*)d_in[7];
    float* out = (float*)d_out;

    float* ws = (float*)d_ws;
    float* word = ws;                                   // NB*NW*ND
    float* trig = word + (size_t)NB * NW * ND;          // NB*NT*ND
    float* ent = trig + (size_t)NB * NT * ND;           // NB*NE*ND
    float* pre_t = ent + (size_t)NB * NE * ND;          // NB*NT*NH
    float* pre_e = pre_t + (size_t)NB * NT * NH;        // NB*NE*NH

    hipMemsetAsync(d_out, 0, (size_t)out_size * sizeof(float), stream);

    word_mean_kernel<<<NB * NW, 256, 0, stream>>>(piece, widx, word);
    span_mean_kernel<<<NB * (NT + NE), 256, 0, stream>>>(word, tidx, eidx, trig, ent);

    dim3 blk(16, 16);
    pre_gemm_kernel<<<dim3((NB * NT) / 64, 10), blk, 0, stream>>>(trig, W0, 0, pre_t);
    pre_gemm_kernel<<<dim3((NB * NE) / 64, 10), blk, 0, stream>>>(ent, W0, ND, pre_e);

    pair_ffn_kernel<<<dim3(NB * NT, 10), blk, 0, stream>>>(
        trig, ent, W0, b0, pre_t, pre_e, W1, b1, out);
}

// Round 2
// 313.033 us; speedup vs baseline: 4.4257x; 4.4257x over previous
//
#include <hip/hip_runtime.h>
#include <cstddef>
#include <cstdint>

typedef float f32x4 __attribute__((ext_vector_type(4)));
typedef __bf16 bf16x8 __attribute__((ext_vector_type(8)));

constexpr int NB = 16;   // batch
constexpr int NP = 512;  // pieces
constexpr int ND = 1024; // dim
constexpr int NW = 400;  // words
constexpr int NT = 32;   // triggers
constexpr int NE = 64;   // entities
constexpr int NH = 600;  // hidden
constexpr int KW = 4096; // W0t row stride (k dim, all 4 slices)

__device__ inline bf16x8 pack8(float a0, float a1, float a2, float a3,
                               float a4, float a5, float a6, float a7) {
    bf16x8 v;
    v[0] = (__bf16)a0; v[1] = (__bf16)a1; v[2] = (__bf16)a2; v[3] = (__bf16)a3;
    v[4] = (__bf16)a4; v[5] = (__bf16)a5; v[6] = (__bf16)a6; v[7] = (__bf16)a7;
    return v;
}

// ---------------------------------------------------------------------------
// Kernel 1: word means over piece intervals. grid = NB*NW, block = 256.
__global__ __launch_bounds__(256) void word_mean_kernel(
    const float* __restrict__ piece, const int* __restrict__ widx,
    float* __restrict__ word) {
    int bw = blockIdx.x;
    int b = bw / NW;
    int s = widx[bw * 2], e = widx[bw * 2 + 1];
    int col = threadIdx.x * 4;
    const float* base = piece + (size_t)b * NP * ND + col;
    float4 acc = make_float4(0.f, 0.f, 0.f, 0.f);
    for (int r = s; r < e; ++r) {
        float4 v = *(const float4*)(base + (size_t)r * ND);
        acc.x += v.x; acc.y += v.y; acc.z += v.z; acc.w += v.w;
    }
    float inv = 1.0f / (float)(e - s);
    acc.x *= inv; acc.y *= inv; acc.z *= inv; acc.w *= inv;
    *(float4*)(word + (size_t)bw * ND + col) = acc;
}

// ---------------------------------------------------------------------------
// Kernel 2: span means over word intervals (trig + ent in one grid).
__global__ __launch_bounds__(256) void span_mean_kernel(
    const float* __restrict__ word, const int* __restrict__ tidx,
    const int* __restrict__ eidx, float* __restrict__ trig,
    float* __restrict__ ent) {
    int id = blockIdx.x;
    const int* idx;
    float* out;
    int b;
    if (id < NB * NT) {
        b = id / NT; idx = tidx + id * 2; out = trig + (size_t)id * ND;
    } else {
        int id2 = id - NB * NT;
        b = id2 / NE; idx = eidx + id2 * 2; out = ent + (size_t)id2 * ND;
    }
    int s = idx[0], e = idx[1];
    int col = threadIdx.x * 4;
    const float* base = word + (size_t)b * NW * ND + col;
    float4 acc = make_float4(0.f, 0.f, 0.f, 0.f);
    for (int r = s; r < e; ++r) {
        float4 v = *(const float4*)(base + (size_t)r * ND);
        acc.x += v.x; acc.y += v.y; acc.z += v.z; acc.w += v.w;
    }
    float inv = 1.0f / (float)(e - s);
    acc.x *= inv; acc.y *= inv; acc.z *= inv; acc.w *= inv;
    *(float4*)(out + col) = acc;
}

// ---------------------------------------------------------------------------
// Kernel 3: W0 [4096][600] fp32 -> W0t [640][4096] bf16 (zero-pad n>=600).
// grid = (64, 10), block = 256.
__global__ __launch_bounds__(256) void w0_transpose_kernel(
    const float* __restrict__ W0, __bf16* __restrict__ W0t) {
    __shared__ float tile[64][65];
    int kb = blockIdx.x * 64, nb = blockIdx.y * 64;
    int t = threadIdx.x;
    {
        int kr = t >> 2, n0 = (t & 3) * 16;
        const float* src = W0 + (size_t)(kb + kr) * NH + nb + n0;
#pragma unroll
        for (int j = 0; j < 16; ++j) {
            int n = nb + n0 + j;
            tile[kr][n0 + j] = (n < NH) ? src[j] : 0.0f;
        }
    }
    __syncthreads();
    {
        int nr = t >> 2, k0 = (t & 3) * 16;
        __bf16* dst = W0t + (size_t)(nb + nr) * KW + kb + k0;
        bf16x8 o0, o1;
#pragma unroll
        for (int j = 0; j < 8; ++j) o0[j] = (__bf16)tile[k0 + j][nr];
#pragma unroll
        for (int j = 0; j < 8; ++j) o1[j] = (__bf16)tile[k0 + 8 + j][nr];
        *(bf16x8*)dst = o0;
        *(bf16x8*)(dst + 8) = o1;
    }
}

// ---------------------------------------------------------------------------
// Kernel 4: pre-projection GEMMs via MFMA.
// pre_t = trig @ W0[0:1024]; pre_e = ent @ W0[1024:2048].
// Tile 128x128, BK=64. grid = (4 + 8, 5), block 256.
__global__ __launch_bounds__(256) void pre_mfma_kernel(
    const float* __restrict__ trig, const float* __restrict__ ent,
    const __bf16* __restrict__ W0t, float* __restrict__ pre_t,
    float* __restrict__ pre_e) {
    __shared__ __bf16 As[128][64];
    __shared__ __bf16 Bs[128][64];
    int mb = blockIdx.x, nc = blockIdx.y;
    const float* A;
    float* C;
    int kofs, mbase;
    if (mb < 4) { A = trig; C = pre_t; kofs = 0;  mbase = mb * 128; }
    else        { A = ent;  C = pre_e; kofs = ND; mbase = (mb - 4) * 128; }
    int tid = threadIdx.x;
    int l = tid & 63, w = tid >> 6, rw = w & 1, cw = w >> 1;
    int q = l >> 4, l15 = l & 15, sa = l15 & 7;
    f32x4 acc[4][4] = {};

    for (int kb = 0; kb < ND; kb += 64) {
        __syncthreads();
#pragma unroll
        for (int p = 0; p < 4; ++p) {
            int L = p * 256 + tid;
            int row = L >> 3, c = L & 7;
            int sw8 = ((c ^ (row & 7)) << 3);
            const float* ar = A + (size_t)(mbase + row) * ND + kb + c * 8;
            float4 a0 = *(const float4*)ar, a1 = *(const float4*)(ar + 4);
            *(bf16x8*)&As[row][sw8] =
                pack8(a0.x, a0.y, a0.z, a0.w, a1.x, a1.y, a1.z, a1.w);
            const __bf16* wsrc =
                W0t + (size_t)(nc * 128 + row) * KW + kofs + kb + c * 8;
            *(bf16x8*)&Bs[row][sw8] = *(const bf16x8*)wsrc;
        }
        __syncthreads();
#pragma unroll
        for (int ks = 0; ks < 2; ++ks) {
            int coff = ((q ^ sa) ^ (ks << 2)) << 3;
            bf16x8 af[4];
#pragma unroll
            for (int mt = 0; mt < 4; ++mt)
                af[mt] = *(const bf16x8*)&As[64 * rw + 16 * mt + l15][coff];
#pragma unroll
            for (int nt = 0; nt < 4; ++nt) {
                bf16x8 bf = *(const bf16x8*)&Bs[64 * cw + 16 * nt + l15][coff];
#pragma unroll
                for (int mt = 0; mt < 4; ++mt)
                    acc[mt][nt] = __builtin_amdgcn_mfma_f32_16x16x32_bf16(
                        af[mt], bf, acc[mt][nt], 0, 0, 0);
            }
        }
    }
#pragma unroll
    for (int mt = 0; mt < 4; ++mt)
#pragma unroll
        for (int r = 0; r < 4; ++r) {
            int grow = mbase + 64 * rw + 16 * mt + 4 * q + r;
            float* crow = C + (size_t)grow * NH;
#pragma unroll
            for (int nt = 0; nt < 4; ++nt) {
                int n = nc * 128 + 64 * cw + 16 * nt + l15;
                if (n < NH) crow[n] = acc[mt][nt][r];
            }
        }
}

// ---------------------------------------------------------------------------
// Kernel 5: pairwise GEMM + fused FFN epilogue via MFMA.
// Block = (b, trigger-pair, n-chunk of 128). M=128 (2 triggers x 64 entities),
// N=128, K=2048 (t*e vs W0c, |t-e| vs W0d). grid = (16,16,5), block 256.
__global__ __launch_bounds__(256) void pair_mfma_kernel(
    const float* __restrict__ trig, const float* __restrict__ ent,
    const __bf16* __restrict__ W0t, const float* __restrict__ b0,
    const float* __restrict__ pre_t, const float* __restrict__ pre_e,
    const float* __restrict__ W1, const float* __restrict__ b1,
    float* __restrict__ out) {
    __shared__ __bf16 Xs[128][64];
    __shared__ __bf16 Bs[128][64];
    int b = blockIdx.x, tp = blockIdx.y, nc = blockIdx.z;
    int tid = threadIdx.x;
    int l = tid & 63, w = tid >> 6, rw = w & 1, cw = w >> 1;
    int q = l >> 4, l15 = l & 15, sa = l15 & 7;
    const float* t0row = trig + (size_t)(b * NT + tp * 2 + 0) * ND;
    const float* t1row = trig + (size_t)(b * NT + tp * 2 + 1) * ND;
    const float* ebase = ent + (size_t)(b * NE) * ND;
    f32x4 acc[4][4] = {};

    for (int kb = 0; kb < 2 * ND; kb += 64) {
        __syncthreads();
        bool prod = (kb < ND);
        int kgb = prod ? kb : kb - ND;
        // X staging: rows 0..63 = trigger0 x e, rows 64..127 = trigger1 x e
#pragma unroll
        for (int p = 0; p < 2; ++p) {
            int L = p * 256 + tid;   // 0..511 -> (e, chunk)
            int e = L >> 3, c = L & 7;
            int kg = kgb + c * 8;
            const float* er = ebase + (size_t)e * ND + kg;
            float4 e0 = *(const float4*)er, e1 = *(const float4*)(er + 4);
            float4 ta0 = *(const float4*)(t0row + kg);
            float4 ta1 = *(const float4*)(t0row + kg + 4);
            float4 tb0 = *(const float4*)(t1row + kg);
            float4 tb1 = *(const float4*)(t1row + kg + 4);
            bf16x8 v0, v1;
            if (prod) {
                v0 = pack8(ta0.x * e0.x, ta0.y * e0.y, ta0.z * e0.z, ta0.w * e0.w,
                           ta1.x * e1.x, ta1.y * e1.y, ta1.z * e1.z, ta1.w * e1.w);
                v1 = pack8(tb0.x * e0.x, tb0.y * e0.y, tb0.z * e0.z, tb0.w * e0.w,
                           tb1.x * e1.x, tb1.y * e1.y, tb1.z * e1.z, tb1.w * e1.w);
            } else {
                v0 = pack8(fabsf(ta0.x - e0.x), fabsf(ta0.y - e0.y),
                           fabsf(ta0.z - e0.z), fabsf(ta0.w - e0.w),
                           fabsf(ta1.x - e1.x), fabsf(ta1.y - e1.y),
                           fabsf(ta1.z - e1.z), fabsf(ta1.w - e1.w));
                v1 = pack8(fabsf(tb0.x - e0.x), fabsf(tb0.y - e0.y),
                           fabsf(tb0.z - e0.z), fabsf(tb0.w - e0.w),
                           fabsf(tb1.x - e1.x), fabsf(tb1.y - e1.y),
                           fabsf(tb1.z - e1.z), fabsf(tb1.w - e1.w));
            }
            int sw8 = ((c ^ (e & 7)) << 3);   // (64+e)&7 == e&7
            *(bf16x8*)&Xs[e][sw8] = v0;
            *(bf16x8*)&Xs[64 + e][sw8] = v1;
        }
        // W staging
#pragma unroll
        for (int p = 0; p < 4; ++p) {
            int L = p * 256 + tid;
            int row = L >> 3, c = L & 7;
            const __bf16* wsrc =
                W0t + (size_t)(nc * 128 + row) * KW + 2 * ND + kb + c * 8;
            *(bf16x8*)&Bs[row][((c ^ (row & 7)) << 3)] = *(const bf16x8*)wsrc;
        }
        __syncthreads();
#pragma unroll
        for (int ks = 0; ks < 2; ++ks) {
            int coff = ((q ^ sa) ^ (ks << 2)) << 3;
            bf16x8 af[4];
#pragma unroll
            for (int mt = 0; mt < 4; ++mt)
                af[mt] = *(const bf16x8*)&Xs[64 * rw + 16 * mt + l15][coff];
#pragma unroll
            for (int nt = 0; nt < 4; ++nt) {
                bf16x8 bf = *(const bf16x8*)&Bs[64 * cw + 16 * nt + l15][coff];
#pragma unroll
                for (int mt = 0; mt < 4; ++mt)
                    acc[mt][nt] = __builtin_amdgcn_mfma_f32_16x16x32_bf16(
                        af[mt], bf, acc[mt][nt], 0, 0, 0);
            }
        }
    }

    // Epilogue: h = relu(acc + pre_t + pre_e + b0); out += h @ W1 (+ b1 once)
    int tglob = b * NT + tp * 2 + rw;
    const float* preT = pre_t + (size_t)tglob * NH;
    float w10[4], w11[4], b0v[4], ptv[4];
    int nbase = nc * 128 + 64 * cw + l15;
#pragma unroll
    for (int nt = 0; nt < 4; ++nt) {
        int n = nbase + 16 * nt;
        bool v = n < NH;
        w10[nt] = v ? W1[2 * n] : 0.f;
        w11[nt] = v ? W1[2 * n + 1] : 0.f;
        b0v[nt] = v ? b0[n] : 0.f;
        ptv[nt] = v ? preT[n] : 0.f;
    }
    float b10 = b1[0], b11 = b1[1];
    bool lead = (l15 == 0);
    bool addb = (nc == 0) && (cw == 0);
#pragma unroll
    for (int mt = 0; mt < 4; ++mt) {
#pragma unroll
        for (int r = 0; r < 4; ++r) {
            int e = 16 * mt + 4 * q + r;
            const float* preE = pre_e + (size_t)(b * NE + e) * NH;
            float s0 = 0.f, s1 = 0.f;
#pragma unroll
            for (int nt = 0; nt < 4; ++nt) {
                int n = nbase + 16 * nt;
                float pe = (n < NH) ? preE[n] : 0.f;
                float h = acc[mt][nt][r] + ptv[nt] + pe + b0v[nt];
                h = fmaxf(h, 0.f);
                s0 += h * w10[nt];
                s1 += h * w11[nt];
            }
#pragma unroll
            for (int m = 8; m >= 1; m >>= 1) {
                s0 += __shfl_xor(s0, m);
                s1 += __shfl_xor(s1, m);
            }
            if (lead) {
                if (addb) { s0 += b10; s1 += b11; }
                float* o = out + ((size_t)(tglob * NE + e)) * 2;
                atomicAdd(o, s0);
                atomicAdd(o + 1, s1);
            }
        }
    }
}

// ---------------------------------------------------------------------------
extern "C" void kernel_launch(void* const* d_in, const int* in_sizes, int n_in,
                              void* d_out, int out_size, void* d_ws,
                              size_t ws_size, hipStream_t stream) {
    const float* piece = (const float*)d_in[0];
    const int* widx = (const int*)d_in[1];
    const int* tidx = (const int*)d_in[2];
    const int* eidx = (const int*)d_in[3];
    const float* W0 = (const float*)d_in[4];
    const float* b0 = (const float*)d_in[5];
    const float* W1 = (const float*)d_in[6];
    const float* b1 = (const float*)d_in[7];
    float* out = (float*)d_out;

    float* ws = (float*)d_ws;
    float* word = ws;                               // NB*NW*ND f32 (dead after span_mean)
    float* trig = word + (size_t)NB * NW * ND;      // NB*NT*ND f32
    float* ent = trig + (size_t)NB * NT * ND;       // NB*NE*ND f32
    float* pre_t = ent + (size_t)NB * NE * ND;      // NB*NT*NH f32
    float* pre_e = pre_t + (size_t)NB * NT * NH;    // NB*NE*NH f32
    __bf16* W0t = (__bf16*)word;                    // 640*4096 bf16, aliases dead `word`

    hipMemsetAsync(d_out, 0, (size_t)out_size * sizeof(float), stream);

    word_mean_kernel<<<NB * NW, 256, 0, stream>>>(piece, widx, word);
    span_mean_kernel<<<NB * (NT + NE), 256, 0, stream>>>(word, tidx, eidx, trig, ent);
    // word is dead from here on; transpose overwrites it with W0t
    w0_transpose_kernel<<<dim3(64, 10), 256, 0, stream>>>(W0, W0t);
    pre_mfma_kernel<<<dim3(12, 5), 256, 0, stream>>>(trig, ent, W0t, pre_t, pre_e);
    pair_mfma_kernel<<<dim3(16, 16, 5), 256, 0, stream>>>(
        trig, ent, W0t, b0, pre_t, pre_e, W1, b1, out);
}

// Round 3
// 297.215 us; speedup vs baseline: 4.6613x; 1.0532x over previous
//
#include <hip/hip_runtime.h>
#include <cstddef>
#include <cstdint>

typedef float f32x4 __attribute__((ext_vector_type(4)));
typedef __bf16 bf16x8 __attribute__((ext_vector_type(8)));

constexpr int NB = 16;   // batch
constexpr int NP = 512;  // pieces
constexpr int ND = 1024; // dim
constexpr int NW = 400;  // words
constexpr int NT = 32;   // triggers
constexpr int NE = 64;   // entities
constexpr int NH = 600;  // hidden
// W0sw: [nc=5][kb=64] tile images, each image = 128 rows x 64 k bf16 with the
// XOR-chunk swizzle baked in: elem(row, c, j) at row*64 + (c^(row&7))*8 + j,
// value = W0[kb*64 + c*8 + j][nc*128 + row] (0-padded for n >= 600).
constexpr int IMG = 128 * 64; // elems per image

__device__ inline bf16x8 pack8(float a0, float a1, float a2, float a3,
                               float a4, float a5, float a6, float a7) {
    bf16x8 v;
    v[0] = (__bf16)a0; v[1] = (__bf16)a1; v[2] = (__bf16)a2; v[3] = (__bf16)a3;
    v[4] = (__bf16)a4; v[5] = (__bf16)a5; v[6] = (__bf16)a6; v[7] = (__bf16)a7;
    return v;
}

__device__ inline void dma16(const void* g, void* l) {
    __builtin_amdgcn_global_load_lds(
        (const __attribute__((address_space(1))) uint32_t*)g,
        (__attribute__((address_space(3))) uint32_t*)l, 16, 0, 0);
}

// ---------------------------------------------------------------------------
// Kernel 1: word means over piece intervals. grid = NB*NW, block = 256.
__global__ __launch_bounds__(256) void word_mean_kernel(
    const float* __restrict__ piece, const int* __restrict__ widx,
    float* __restrict__ word) {
    int bw = blockIdx.x;
    int b = bw / NW;
    int s = widx[bw * 2], e = widx[bw * 2 + 1];
    int col = threadIdx.x * 4;
    const float* base = piece + (size_t)b * NP * ND + col;
    float4 acc = make_float4(0.f, 0.f, 0.f, 0.f);
    for (int r = s; r < e; ++r) {
        float4 v = *(const float4*)(base + (size_t)r * ND);
        acc.x += v.x; acc.y += v.y; acc.z += v.z; acc.w += v.w;
    }
    float inv = 1.0f / (float)(e - s);
    acc.x *= inv; acc.y *= inv; acc.z *= inv; acc.w *= inv;
    *(float4*)(word + (size_t)bw * ND + col) = acc;
}

// ---------------------------------------------------------------------------
// Kernel 2: span means over word intervals (trig + ent in one grid).
__global__ __launch_bounds__(256) void span_mean_kernel(
    const float* __restrict__ word, const int* __restrict__ tidx,
    const int* __restrict__ eidx, float* __restrict__ trig,
    float* __restrict__ ent) {
    int id = blockIdx.x;
    const int* idx;
    float* out;
    int b;
    if (id < NB * NT) {
        b = id / NT; idx = tidx + id * 2; out = trig + (size_t)id * ND;
    } else {
        int id2 = id - NB * NT;
        b = id2 / NE; idx = eidx + id2 * 2; out = ent + (size_t)id2 * ND;
    }
    int s = idx[0], e = idx[1];
    int col = threadIdx.x * 4;
    const float* base = word + (size_t)b * NW * ND + col;
    float4 acc = make_float4(0.f, 0.f, 0.f, 0.f);
    for (int r = s; r < e; ++r) {
        float4 v = *(const float4*)(base + (size_t)r * ND);
        acc.x += v.x; acc.y += v.y; acc.z += v.z; acc.w += v.w;
    }
    float inv = 1.0f / (float)(e - s);
    acc.x *= inv; acc.y *= inv; acc.z *= inv; acc.w *= inv;
    *(float4*)(out + col) = acc;
}

// ---------------------------------------------------------------------------
// Kernel 3: W0 [4096][600] f32 -> swizzled bf16 tile images W0sw[5][64][IMG].
// grid = (kb=64, nc=5), block = 256.
__global__ __launch_bounds__(256) void w0_swizzle_kernel(
    const float* __restrict__ W0, __bf16* __restrict__ W0sw) {
    __shared__ float T[64][132];   // [k local][n local], padded
    int kb = blockIdx.x, nc = blockIdx.y;
    int t = threadIdx.x;
    {
        int kl = t >> 2;
        int n0 = (t & 3) * 32;
        int kg = kb * 64 + kl;
        const float* src = W0 + (size_t)kg * NH + nc * 128 + n0;
#pragma unroll
        for (int g = 0; g < 8; ++g) {
            int n = nc * 128 + n0 + g * 4;
            float4 v = (n < NH) ? *(const float4*)(src + g * 4)
                                : make_float4(0.f, 0.f, 0.f, 0.f);
            *(float4*)&T[kl][n0 + g * 4] = v;
        }
    }
    __syncthreads();
    __bf16* img = W0sw + ((size_t)nc * 64 + kb) * IMG;
#pragma unroll
    for (int s = 0; s < 4; ++s) {
        int idx = t * 4 + s;       // (row, c)
        int row = idx >> 3, c = idx & 7;
        bf16x8 v = pack8(T[c * 8 + 0][row], T[c * 8 + 1][row],
                         T[c * 8 + 2][row], T[c * 8 + 3][row],
                         T[c * 8 + 4][row], T[c * 8 + 5][row],
                         T[c * 8 + 6][row], T[c * 8 + 7][row]);
        *(bf16x8*)&img[row * 64 + ((c ^ (row & 7)) << 3)] = v;
    }
}

// ---------------------------------------------------------------------------
// Kernel 4: pre-projection GEMMs, 64x64 tiles, 1 wave per block.
// grid = (24 mtile [0..7 trig, 8..23 ent], 10 ntile), block = 64.
__global__ __launch_bounds__(64) void pre_mfma_kernel(
    const float* __restrict__ trig, const float* __restrict__ ent,
    const __bf16* __restrict__ W0sw, float* __restrict__ pre_t,
    float* __restrict__ pre_e) {
    __shared__ __bf16 As[64 * 64];
    __shared__ __bf16 Bs[64 * 64];
    int mt8 = blockIdx.x, ntile = blockIdx.y;
    const float* A;
    float* C;
    int kbofs, mbase;
    if (mt8 < 8) { A = trig; C = pre_t; kbofs = 0;  mbase = mt8 * 64; }
    else         { A = ent;  C = pre_e; kbofs = 16; mbase = (mt8 - 8) * 64; }
    int lane = threadIdx.x;
    int q = lane >> 4, l15 = lane & 15, sa = l15 & 7;
    int nc = ntile >> 1, half = ntile & 1;
    const __bf16* imgbase = W0sw + ((size_t)nc * 64 + kbofs) * IMG + half * 4096;
    f32x4 acc[4][4] = {};

    for (int it = 0; it < 16; ++it) {
        __syncthreads();
        // B: 8 KB half-image via DMA
        const __bf16* img = imgbase + (size_t)it * IMG;
#pragma unroll
        for (int i = 0; i < 8; ++i)
            dma16(img + i * 512 + lane * 8, (__bf16*)Bs + i * 512);
        // A: f32 -> bf16 swizzled
#pragma unroll
        for (int s = 0; s < 8; ++s) {
            int L = s * 64 + lane;
            int r = L >> 3, c = L & 7;
            const float* ar = A + (size_t)(mbase + r) * ND + it * 64 + c * 8;
            float4 a0 = *(const float4*)ar, a1 = *(const float4*)(ar + 4);
            *(bf16x8*)&As[r * 64 + ((c ^ (r & 7)) << 3)] =
                pack8(a0.x, a0.y, a0.z, a0.w, a1.x, a1.y, a1.z, a1.w);
        }
        __syncthreads();
#pragma unroll
        for (int ks = 0; ks < 2; ++ks) {
            int coff = ((q ^ sa) ^ (ks << 2)) << 3;
            bf16x8 af[4];
#pragma unroll
            for (int mt = 0; mt < 4; ++mt)
                af[mt] = *(const bf16x8*)&As[(16 * mt + l15) * 64 + coff];
#pragma unroll
            for (int nt = 0; nt < 4; ++nt) {
                bf16x8 bf = *(const bf16x8*)&Bs[(16 * nt + l15) * 64 + coff];
#pragma unroll
                for (int mt = 0; mt < 4; ++mt)
                    acc[mt][nt] = __builtin_amdgcn_mfma_f32_16x16x32_bf16(
                        af[mt], bf, acc[mt][nt], 0, 0, 0);
            }
        }
    }
#pragma unroll
    for (int mt = 0; mt < 4; ++mt)
#pragma unroll
        for (int r = 0; r < 4; ++r) {
            float* crow = C + (size_t)(mbase + 16 * mt + 4 * q + r) * NH;
#pragma unroll
            for (int nt = 0; nt < 4; ++nt) {
                int n = ntile * 64 + 16 * nt + l15;
                if (n < NH) crow[n] = acc[mt][nt][r];
            }
        }
}

// ---------------------------------------------------------------------------
// Kernel 5: pairwise GEMM + fused FFN epilogue. Single-barrier double-buffered
// pipeline; B staged by global_load_lds from pre-swizzled images.
// grid = (16 b, 16 tp, 5 nc), block = 256 (4 waves).
__global__ __launch_bounds__(256, 2) void pair_mfma_kernel(
    const float* __restrict__ trig, const float* __restrict__ ent,
    const __bf16* __restrict__ W0sw, const float* __restrict__ b0,
    const float* __restrict__ pre_t, const float* __restrict__ pre_e,
    const float* __restrict__ W1, const float* __restrict__ b1,
    float* __restrict__ out) {
    __shared__ __bf16 Xs[2][128 * 64];
    __shared__ __bf16 Bs[2][128 * 64];
    int b = blockIdx.x, tp = blockIdx.y, nc = blockIdx.z;
    int tid = threadIdx.x;
    int lane = tid & 63, w = tid >> 6, rw = w & 1, cw = w >> 1;
    int q = lane >> 4, l15 = lane & 15, sa = l15 & 7;
    const float* t0row = trig + (size_t)(b * NT + tp * 2 + 0) * ND;
    const float* t1row = trig + (size_t)(b * NT + tp * 2 + 1) * ND;
    const float* ebase = ent + (size_t)(b * NE) * ND;
    // pair slice of W0 (rows 2048..4095) = images kb 32..63
    const __bf16* imgbase = W0sw + ((size_t)nc * 64 + 32) * IMG;
    f32x4 acc[4][4] = {};
    float4 xp[12];

    // --- helpers (lambdas keep the pipeline body readable) ---
    auto stage_b = [&](int it, int buf) {
        const __bf16* img = imgbase + (size_t)it * IMG + w * 2048;
        __bf16* lds = (__bf16*)Bs[buf] + w * 2048;
#pragma unroll
        for (int i = 0; i < 4; ++i)
            dma16(img + i * 512 + lane * 8, lds + i * 512);
    };
    auto load_x = [&](int it) {
        int kgb = (it < 16) ? it * 64 : (it - 16) * 64;
#pragma unroll
        for (int p = 0; p < 2; ++p) {
            int L = p * 256 + tid;
            int e = L >> 3, c = L & 7;
            int kg = kgb + c * 8;
            const float* er = ebase + (size_t)e * ND + kg;
            xp[p * 6 + 0] = *(const float4*)er;
            xp[p * 6 + 1] = *(const float4*)(er + 4);
            xp[p * 6 + 2] = *(const float4*)(t0row + kg);
            xp[p * 6 + 3] = *(const float4*)(t0row + kg + 4);
            xp[p * 6 + 4] = *(const float4*)(t1row + kg);
            xp[p * 6 + 5] = *(const float4*)(t1row + kg + 4);
        }
    };
    auto write_x = [&](int it, int buf) {
        bool prod = (it < 16);
#pragma unroll
        for (int p = 0; p < 2; ++p) {
            int L = p * 256 + tid;
            int e = L >> 3, c = L & 7;
            float4 e0 = xp[p * 6 + 0], e1 = xp[p * 6 + 1];
            float4 ta0 = xp[p * 6 + 2], ta1 = xp[p * 6 + 3];
            float4 tb0 = xp[p * 6 + 4], tb1 = xp[p * 6 + 5];
            bf16x8 v0, v1;
            if (prod) {
                v0 = pack8(ta0.x * e0.x, ta0.y * e0.y, ta0.z * e0.z, ta0.w * e0.w,
                           ta1.x * e1.x, ta1.y * e1.y, ta1.z * e1.z, ta1.w * e1.w);
                v1 = pack8(tb0.x * e0.x, tb0.y * e0.y, tb0.z * e0.z, tb0.w * e0.w,
                           tb1.x * e1.x, tb1.y * e1.y, tb1.z * e1.z, tb1.w * e1.w);
            } else {
                v0 = pack8(fabsf(ta0.x - e0.x), fabsf(ta0.y - e0.y),
                           fabsf(ta0.z - e0.z), fabsf(ta0.w - e0.w),
                           fabsf(ta1.x - e1.x), fabsf(ta1.y - e1.y),
                           fabsf(ta1.z - e1.z), fabsf(ta1.w - e1.w));
                v1 = pack8(fabsf(tb0.x - e0.x), fabsf(tb0.y - e0.y),
                           fabsf(tb0.z - e0.z), fabsf(tb0.w - e0.w),
                           fabsf(tb1.x - e1.x), fabsf(tb1.y - e1.y),
                           fabsf(tb1.z - e1.z), fabsf(tb1.w - e1.w));
            }
            int sw8 = ((c ^ (e & 7)) << 3);
            *(bf16x8*)&Xs[buf][e * 64 + sw8] = v0;
            *(bf16x8*)&Xs[buf][(64 + e) * 64 + sw8] = v1;
        }
    };
    auto mfma_tile = [&](int buf) {
#pragma unroll
        for (int ks = 0; ks < 2; ++ks) {
            int coff = ((q ^ sa) ^ (ks << 2)) << 3;
            bf16x8 af[4];
#pragma unroll
            for (int mt = 0; mt < 4; ++mt)
                af[mt] = *(const bf16x8*)&Xs[buf][(64 * rw + 16 * mt + l15) * 64 + coff];
#pragma unroll
            for (int nt = 0; nt < 4; ++nt) {
                bf16x8 bf = *(const bf16x8*)&Bs[buf][(64 * cw + 16 * nt + l15) * 64 + coff];
#pragma unroll
                for (int mt = 0; mt < 4; ++mt)
                    acc[mt][nt] = __builtin_amdgcn_mfma_f32_16x16x32_bf16(
                        af[mt], bf, acc[mt][nt], 0, 0, 0);
            }
        }
    };

    // --- pipeline ---
    stage_b(0, 0);
    load_x(0);
    write_x(0, 0);
    __syncthreads();
    for (int it = 0; it < 31; ++it) {
        int cur = it & 1, nxt = cur ^ 1;
        stage_b(it + 1, nxt);   // async DMA into other buffer
        load_x(it + 1);         // global loads into registers
        mfma_tile(cur);         // compute on current buffer
        write_x(it + 1, nxt);   // convert + LDS write
        __syncthreads();        // one barrier per iter (drains DMA too)
    }
    mfma_tile(1);               // tile 31 lives in buffer 1

    // --- epilogue: h = relu(acc + pre_t + pre_e + b0); out += h @ W1 ---
    int tglob = b * NT + tp * 2 + rw;
    const float* preT = pre_t + (size_t)tglob * NH;
    float w10[4], w11[4], b0v[4], ptv[4];
    int nbase = nc * 128 + 64 * cw + l15;
#pragma unroll
    for (int nt = 0; nt < 4; ++nt) {
        int n = nbase + 16 * nt;
        bool v = n < NH;
        w10[nt] = v ? W1[2 * n] : 0.f;
        w11[nt] = v ? W1[2 * n + 1] : 0.f;
        b0v[nt] = v ? b0[n] : 0.f;
        ptv[nt] = v ? preT[n] : 0.f;
    }
    float b10 = b1[0], b11 = b1[1];
    bool lead = (l15 == 0);
    bool addb = (nc == 0) && (cw == 0);
#pragma unroll
    for (int mt = 0; mt < 4; ++mt) {
#pragma unroll
        for (int r = 0; r < 4; ++r) {
            int e = 16 * mt + 4 * q + r;
            const float* preE = pre_e + (size_t)(b * NE + e) * NH;
            float s0 = 0.f, s1 = 0.f;
#pragma unroll
            for (int nt = 0; nt < 4; ++nt) {
                int n = nbase + 16 * nt;
                float pe = (n < NH) ? preE[n] : 0.f;
                float h = acc[mt][nt][r] + ptv[nt] + pe + b0v[nt];
                h = fmaxf(h, 0.f);
                s0 += h * w10[nt];
                s1 += h * w11[nt];
            }
#pragma unroll
            for (int m = 8; m >= 1; m >>= 1) {
                s0 += __shfl_xor(s0, m);
                s1 += __shfl_xor(s1, m);
            }
            if (lead) {
                if (addb) { s0 += b10; s1 += b11; }
                float* o = out + ((size_t)(tglob * NE + e)) * 2;
                atomicAdd(o, s0);
                atomicAdd(o + 1, s1);
            }
        }
    }
}

// ---------------------------------------------------------------------------
extern "C" void kernel_launch(void* const* d_in, const int* in_sizes, int n_in,
                              void* d_out, int out_size, void* d_ws,
                              size_t ws_size, hipStream_t stream) {
    const float* piece = (const float*)d_in[0];
    const int* widx = (const int*)d_in[1];
    const int* tidx = (const int*)d_in[2];
    const int* eidx = (const int*)d_in[3];
    const float* W0 = (const float*)d_in[4];
    const float* b0 = (const float*)d_in[5];
    const float* W1 = (const float*)d_in[6];
    const float* b1 = (const float*)d_in[7];
    float* out = (float*)d_out;

    float* ws = (float*)d_ws;
    float* word = ws;                               // NB*NW*ND f32 (dead after span_mean)
    float* trig = word + (size_t)NB * NW * ND;      // NB*NT*ND f32
    float* ent = trig + (size_t)NB * NT * ND;       // NB*NE*ND f32
    float* pre_t = ent + (size_t)NB * NE * ND;      // NB*NT*NH f32
    float* pre_e = pre_t + (size_t)NB * NT * NH;    // NB*NE*NH f32
    __bf16* W0sw = (__bf16*)word;                   // 5*64*IMG bf16, aliases dead `word`

    hipMemsetAsync(d_out, 0, (size_t)out_size * sizeof(float), stream);

    word_mean_kernel<<<NB * NW, 256, 0, stream>>>(piece, widx, word);
    span_mean_kernel<<<NB * (NT + NE), 256, 0, stream>>>(word, tidx, eidx, trig, ent);
    // word is dead from here on; swizzle overwrites it with W0sw
    w0_swizzle_kernel<<<dim3(64, 5), 256, 0, stream>>>(W0, W0sw);
    pre_mfma_kernel<<<dim3(24, 10), 64, 0, stream>>>(trig, ent, W0sw, pre_t, pre_e);
    pair_mfma_kernel<<<dim3(16, 16, 5), 256, 0, stream>>>(
        trig, ent, W0sw, b0, pre_t, pre_e, W1, b1, out);
}

// Round 4
// 271.109 us; speedup vs baseline: 5.1101x; 1.0963x over previous
//
#include <hip/hip_runtime.h>
#include <cstddef>
#include <cstdint>

typedef float f32x4 __attribute__((ext_vector_type(4)));
typedef __bf16 bf16x8 __attribute__((ext_vector_type(8)));
typedef __bf16 bf16x4 __attribute__((ext_vector_type(4)));

constexpr int NB = 16;   // batch
constexpr int NP = 512;  // pieces
constexpr int ND = 1024; // dim
constexpr int NW = 400;  // words
constexpr int NT = 32;   // triggers
constexpr int NE = 64;   // entities
constexpr int NH = 600;  // hidden
// W0pre: [nc=5][kb=32] images (128n x 64k bf16, XOR-swizzled) for slices a,b.
// W0pair: [nc=5][it=16] images (128n x 128k bf16): chunks 0-7 = W0c k-slice,
//   chunks 8-15 = W0d k-slice; pos = (c&8) | ((c^(n&7))&7).
constexpr int IMGP = 128 * 64;   // W0pre image elems
constexpr int IMGQ = 128 * 128;  // W0pair image elems

__device__ inline bf16x8 pack8(float a0, float a1, float a2, float a3,
                               float a4, float a5, float a6, float a7) {
    bf16x8 v;
    v[0] = (__bf16)a0; v[1] = (__bf16)a1; v[2] = (__bf16)a2; v[3] = (__bf16)a3;
    v[4] = (__bf16)a4; v[5] = (__bf16)a5; v[6] = (__bf16)a6; v[7] = (__bf16)a7;
    return v;
}

__device__ inline void dma16(const void* g, void* l) {
    __builtin_amdgcn_global_load_lds(
        (const __attribute__((address_space(1))) uint32_t*)g,
        (__attribute__((address_space(3))) uint32_t*)l, 16, 0, 0);
}

__device__ inline float bflo(uint32_t d) {
    union { uint32_t u; float f; } c; c.u = d << 16; return c.f;
}
__device__ inline float bfhi(uint32_t d) {
    union { uint32_t u; float f; } c; c.u = d & 0xFFFF0000u; return c.f;
}

// ---------------------------------------------------------------------------
// Kernel 1: word means over piece intervals. grid = NB*NW, block = 256.
__global__ __launch_bounds__(256) void word_mean_kernel(
    const float* __restrict__ piece, const int* __restrict__ widx,
    float* __restrict__ word) {
    int bw = blockIdx.x;
    int b = bw / NW;
    int s = widx[bw * 2], e = widx[bw * 2 + 1];
    int col = threadIdx.x * 4;
    const float* base = piece + (size_t)b * NP * ND + col;
    float4 acc = make_float4(0.f, 0.f, 0.f, 0.f);
    for (int r = s; r < e; ++r) {
        float4 v = *(const float4*)(base + (size_t)r * ND);
        acc.x += v.x; acc.y += v.y; acc.z += v.z; acc.w += v.w;
    }
    float inv = 1.0f / (float)(e - s);
    acc.x *= inv; acc.y *= inv; acc.z *= inv; acc.w *= inv;
    *(float4*)(word + (size_t)bw * ND + col) = acc;
}

// ---------------------------------------------------------------------------
// Kernel 2: span means over word intervals (trig + ent in one grid).
__global__ __launch_bounds__(256) void span_mean_kernel(
    const float* __restrict__ word, const int* __restrict__ tidx,
    const int* __restrict__ eidx, float* __restrict__ trig,
    float* __restrict__ ent) {
    int id = blockIdx.x;
    const int* idx;
    float* out;
    int b;
    if (id < NB * NT) {
        b = id / NT; idx = tidx + id * 2; out = trig + (size_t)id * ND;
    } else {
        int id2 = id - NB * NT;
        b = id2 / NE; idx = eidx + id2 * 2; out = ent + (size_t)id2 * ND;
    }
    int s = idx[0], e = idx[1];
    int col = threadIdx.x * 4;
    const float* base = word + (size_t)b * NW * ND + col;
    float4 acc = make_float4(0.f, 0.f, 0.f, 0.f);
    for (int r = s; r < e; ++r) {
        float4 v = *(const float4*)(base + (size_t)r * ND);
        acc.x += v.x; acc.y += v.y; acc.z += v.z; acc.w += v.w;
    }
    float inv = 1.0f / (float)(e - s);
    acc.x *= inv; acc.y *= inv; acc.z *= inv; acc.w *= inv;
    *(float4*)(out + col) = acc;
}

// ---------------------------------------------------------------------------
// Kernel 3: W0 [4096][600] f32 -> swizzled bf16 images (W0pre + W0pair).
// grid = (kb=64, nc=5), block = 256.
__global__ __launch_bounds__(256) void w0_swizzle_kernel(
    const float* __restrict__ W0, __bf16* __restrict__ W0pre,
    __bf16* __restrict__ W0pair) {
    __shared__ float T[64][132];   // [k local][n local], padded
    int kb = blockIdx.x, nc = blockIdx.y;
    int t = threadIdx.x;
    {
        int kl = t >> 2;
        int n0 = (t & 3) * 32;
        int kg = kb * 64 + kl;
        const float* src = W0 + (size_t)kg * NH + nc * 128 + n0;
#pragma unroll
        for (int g = 0; g < 8; ++g) {
            int n = nc * 128 + n0 + g * 4;
            float4 v = (n < NH) ? *(const float4*)(src + g * 4)
                                : make_float4(0.f, 0.f, 0.f, 0.f);
            *(float4*)&T[kl][n0 + g * 4] = v;
        }
    }
    __syncthreads();
#pragma unroll
    for (int s = 0; s < 4; ++s) {
        int idx = t * 4 + s;       // (row=n-local, c=k-chunk)
        int row = idx >> 3, c = idx & 7;
        bf16x8 v = pack8(T[c * 8 + 0][row], T[c * 8 + 1][row],
                         T[c * 8 + 2][row], T[c * 8 + 3][row],
                         T[c * 8 + 4][row], T[c * 8 + 5][row],
                         T[c * 8 + 6][row], T[c * 8 + 7][row]);
        if (kb < 32) {
            __bf16* img = W0pre + ((size_t)nc * 32 + kb) * IMGP;
            *(bf16x8*)&img[row * 64 + ((c ^ (row & 7)) << 3)] = v;
        } else {
            bool isD = kb >= 48;
            int it = kb - (isD ? 48 : 32);
            __bf16* img = W0pair + ((size_t)nc * 16 + it) * IMGQ;
            int pos = ((c ^ (row & 7)) & 7) | (isD ? 8 : 0);
            *(bf16x8*)&img[row * 128 + (pos << 3)] = v;
        }
    }
}

// ---------------------------------------------------------------------------
// Kernel 4: pre-projection GEMMs, 64x64 tiles, 1 wave per block.
// grid = (24 mtile [0..7 trig, 8..23 ent], 10 ntile), block = 64.
__global__ __launch_bounds__(64) void pre_mfma_kernel(
    const float* __restrict__ trig, const float* __restrict__ ent,
    const __bf16* __restrict__ W0pre, float* __restrict__ pre_t,
    float* __restrict__ pre_e) {
    __shared__ __bf16 As[64 * 64];
    __shared__ __bf16 Bs[64 * 64];
    int mt8 = blockIdx.x, ntile = blockIdx.y;
    const float* A;
    float* C;
    int kbofs, mbase;
    if (mt8 < 8) { A = trig; C = pre_t; kbofs = 0;  mbase = mt8 * 64; }
    else         { A = ent;  C = pre_e; kbofs = 16; mbase = (mt8 - 8) * 64; }
    int lane = threadIdx.x;
    int q = lane >> 4, l15 = lane & 15, sa = l15 & 7;
    int nc = ntile >> 1, half = ntile & 1;
    const __bf16* imgbase =
        W0pre + ((size_t)nc * 32 + kbofs) * IMGP + half * 4096;
    f32x4 acc[4][4] = {};

    for (int it = 0; it < 16; ++it) {
        __syncthreads();
        const __bf16* img = imgbase + (size_t)it * IMGP;
#pragma unroll
        for (int i = 0; i < 8; ++i)
            dma16(img + i * 512 + lane * 8, (__bf16*)Bs + i * 512);
#pragma unroll
        for (int s = 0; s < 8; ++s) {
            int L = s * 64 + lane;
            int r = L >> 3, c = L & 7;
            const float* ar = A + (size_t)(mbase + r) * ND + it * 64 + c * 8;
            float4 a0 = *(const float4*)ar, a1 = *(const float4*)(ar + 4);
            *(bf16x8*)&As[r * 64 + ((c ^ (r & 7)) << 3)] =
                pack8(a0.x, a0.y, a0.z, a0.w, a1.x, a1.y, a1.z, a1.w);
        }
        __syncthreads();
#pragma unroll
        for (int ks = 0; ks < 2; ++ks) {
            int coff = ((q ^ sa) ^ (ks << 2)) << 3;
            bf16x8 af[4];
#pragma unroll
            for (int mt = 0; mt < 4; ++mt)
                af[mt] = *(const bf16x8*)&As[(16 * mt + l15) * 64 + coff];
#pragma unroll
            for (int nt = 0; nt < 4; ++nt) {
                bf16x8 bf = *(const bf16x8*)&Bs[(16 * nt + l15) * 64 + coff];
#pragma unroll
                for (int mt = 0; mt < 4; ++mt)
                    acc[mt][nt] = __builtin_amdgcn_mfma_f32_16x16x32_bf16(
                        af[mt], bf, acc[mt][nt], 0, 0, 0);
            }
        }
    }
#pragma unroll
    for (int mt = 0; mt < 4; ++mt)
#pragma unroll
        for (int r = 0; r < 4; ++r) {
            float* crow = C + (size_t)(mbase + 16 * mt + 4 * q + r) * NH;
#pragma unroll
            for (int nt = 0; nt < 4; ++nt) {
                int n = ntile * 64 + 16 * nt + l15;
                if (n < NH) crow[n] = acc[mt][nt][r];
            }
        }
}

// ---------------------------------------------------------------------------
// Kernel 5: pairwise GEMM + fused FFN epilogue. BK=128 (product|absdiff
// fused per iter), trigger rows cached in LDS, B via global_load_lds from
// pre-swizzled pair images. grid = (16 b, 16 tp, 5 nc), block = 256.
__global__ __launch_bounds__(256, 2) void pair_mfma_kernel(
    const float* __restrict__ trig, const float* __restrict__ ent,
    const __bf16* __restrict__ W0pair, const float* __restrict__ b0,
    const float* __restrict__ pre_t, const float* __restrict__ pre_e,
    const float* __restrict__ W1, const float* __restrict__ b1,
    float* __restrict__ out) {
    __shared__ __bf16 Xs[128 * 128];   // 32 KB: rows 0-63 t0 x e, 64-127 t1 x e
    __shared__ __bf16 Bs[128 * 128];   // 32 KB
    __shared__ __bf16 Ts[2 * 1024];    // 4 KB trigger rows (bf16)
    int b = blockIdx.x, tp = blockIdx.y, nc = blockIdx.z;
    int tid = threadIdx.x;
    int lane = tid & 63, w = tid >> 6, rw = w & 1, cw = w >> 1;
    int q = lane >> 4, l15 = lane & 15, sa = l15 & 7;
    int xe = tid >> 2, c4 = tid & 3, e7 = xe & 7;
    const float* t0row = trig + (size_t)(b * NT + tp * 2 + 0) * ND;
    const float* t1row = trig + (size_t)(b * NT + tp * 2 + 1) * ND;
    const float* erow = ent + (size_t)(b * NE + xe) * ND;
    const __bf16* imgbase = W0pair + (size_t)nc * 16 * IMGQ;
    f32x4 acc[4][4] = {};
    float4 ef4[4];

    auto dma_b = [&](int it) {
        const __bf16* img = imgbase + (size_t)it * IMGQ + w * 4096;
        __bf16* lds = (__bf16*)Bs + w * 4096;
#pragma unroll
        for (int i = 0; i < 8; ++i)
            dma16(img + i * 512 + lane * 8, lds + i * 512);
    };
    auto load_e = [&](int it) {
        const float* er = erow + it * 64 + c4 * 16;
#pragma unroll
        for (int i = 0; i < 4; ++i) ef4[i] = *(const float4*)(er + i * 4);
    };
    auto write_x = [&](int it) {
        const uint32_t* tp0 = (const uint32_t*)&Ts[it * 64 + c4 * 16];
        const uint32_t* tp1 = (const uint32_t*)&Ts[1024 + it * 64 + c4 * 16];
        int base0 = xe * 128;
        int base1 = (64 + xe) * 128;
#pragma unroll
        for (int g = 0; g < 2; ++g) {
            float ef[8];
            ef[0] = ef4[2 * g].x; ef[1] = ef4[2 * g].y;
            ef[2] = ef4[2 * g].z; ef[3] = ef4[2 * g].w;
            ef[4] = ef4[2 * g + 1].x; ef[5] = ef4[2 * g + 1].y;
            ef[6] = ef4[2 * g + 1].z; ef[7] = ef4[2 * g + 1].w;
            float t0f[8], t1f[8];
#pragma unroll
            for (int d = 0; d < 4; ++d) {
                uint32_t d0 = tp0[g * 4 + d], d1 = tp1[g * 4 + d];
                t0f[2 * d] = bflo(d0); t0f[2 * d + 1] = bfhi(d0);
                t1f[2 * d] = bflo(d1); t1f[2 * d + 1] = bfhi(d1);
            }
            int pos = (((2 * c4 + g) ^ e7) << 3);
            *(bf16x8*)&Xs[base0 + pos] = pack8(
                t0f[0] * ef[0], t0f[1] * ef[1], t0f[2] * ef[2], t0f[3] * ef[3],
                t0f[4] * ef[4], t0f[5] * ef[5], t0f[6] * ef[6], t0f[7] * ef[7]);
            *(bf16x8*)&Xs[base0 + pos + 64] = pack8(
                fabsf(t0f[0] - ef[0]), fabsf(t0f[1] - ef[1]),
                fabsf(t0f[2] - ef[2]), fabsf(t0f[3] - ef[3]),
                fabsf(t0f[4] - ef[4]), fabsf(t0f[5] - ef[5]),
                fabsf(t0f[6] - ef[6]), fabsf(t0f[7] - ef[7]));
            *(bf16x8*)&Xs[base1 + pos] = pack8(
                t1f[0] * ef[0], t1f[1] * ef[1], t1f[2] * ef[2], t1f[3] * ef[3],
                t1f[4] * ef[4], t1f[5] * ef[5], t1f[6] * ef[6], t1f[7] * ef[7]);
            *(bf16x8*)&Xs[base1 + pos + 64] = pack8(
                fabsf(t1f[0] - ef[0]), fabsf(t1f[1] - ef[1]),
                fabsf(t1f[2] - ef[2]), fabsf(t1f[3] - ef[3]),
                fabsf(t1f[4] - ef[4]), fabsf(t1f[5] - ef[5]),
                fabsf(t1f[6] - ef[6]), fabsf(t1f[7] - ef[7]));
        }
    };
    auto mfma_tile = [&]() {
#pragma unroll
        for (int ks = 0; ks < 4; ++ks) {
            int coff = (((ks & 2) << 2) | ((q | ((ks & 1) << 2)) ^ sa)) << 3;
            bf16x8 af[4];
#pragma unroll
            for (int mt = 0; mt < 4; ++mt)
                af[mt] =
                    *(const bf16x8*)&Xs[(64 * rw + 16 * mt + l15) * 128 + coff];
#pragma unroll
            for (int nt = 0; nt < 4; ++nt) {
                bf16x8 bf =
                    *(const bf16x8*)&Bs[(64 * cw + 16 * nt + l15) * 128 + coff];
#pragma unroll
                for (int mt = 0; mt < 4; ++mt)
                    acc[mt][nt] = __builtin_amdgcn_mfma_f32_16x16x32_bf16(
                        af[mt], bf, acc[mt][nt], 0, 0, 0);
            }
        }
    };

    // --- preamble: trigger rows -> LDS bf16; first tiles in flight ---
    {
        int k0 = tid * 4;
        float4 va = *(const float4*)(t0row + k0);
        float4 vb = *(const float4*)(t1row + k0);
        bf16x4 pa, pb;
        pa[0] = (__bf16)va.x; pa[1] = (__bf16)va.y;
        pa[2] = (__bf16)va.z; pa[3] = (__bf16)va.w;
        pb[0] = (__bf16)vb.x; pb[1] = (__bf16)vb.y;
        pb[2] = (__bf16)vb.z; pb[3] = (__bf16)vb.w;
        *(bf16x4*)&Ts[k0] = pa;
        *(bf16x4*)&Ts[1024 + k0] = pb;
    }
    dma_b(0);
    load_e(0);
    __syncthreads();           // Ts visible (DMA 0 also drains; harmless)
    write_x(0);
    __syncthreads();           // X(0), B(0) ready

    for (int it = 0; it < 16; ++it) {
        if (it < 15) load_e(it + 1);   // prefetch; latency hides under MFMA
        mfma_tile();
        __syncthreads();               // fragment reads done; buffers free
        if (it < 15) {
            dma_b(it + 1);
            write_x(it + 1);
            __syncthreads();           // X/B(it+1) ready (DMA drained)
        }
    }

    // --- epilogue: h = relu(acc + pre_t + pre_e + b0); out += h @ W1 ---
    int tglob = b * NT + tp * 2 + rw;
    const float* preT = pre_t + (size_t)tglob * NH;
    float w10[4], w11[4], b0v[4], ptv[4];
    int nbase = nc * 128 + 64 * cw + l15;
#pragma unroll
    for (int nt = 0; nt < 4; ++nt) {
        int n = nbase + 16 * nt;
        bool v = n < NH;
        w10[nt] = v ? W1[2 * n] : 0.f;
        w11[nt] = v ? W1[2 * n + 1] : 0.f;
        b0v[nt] = v ? b0[n] : 0.f;
        ptv[nt] = v ? preT[n] : 0.f;
    }
    float b10 = b1[0], b11 = b1[1];
    bool lead = (l15 == 0);
    bool addb = (nc == 0) && (cw == 0);
#pragma unroll
    for (int mt = 0; mt < 4; ++mt) {
#pragma unroll
        for (int r = 0; r < 4; ++r) {
            int e = 16 * mt + 4 * q + r;
            const float* preE = pre_e + (size_t)(b * NE + e) * NH;
            float s0 = 0.f, s1 = 0.f;
#pragma unroll
            for (int nt = 0; nt < 4; ++nt) {
                int n = nbase + 16 * nt;
                float pe = (n < NH) ? preE[n] : 0.f;
                float h = acc[mt][nt][r] + ptv[nt] + pe + b0v[nt];
                h = fmaxf(h, 0.f);
                s0 += h * w10[nt];
                s1 += h * w11[nt];
            }
#pragma unroll
            for (int m = 8; m >= 1; m >>= 1) {
                s0 += __shfl_xor(s0, m);
                s1 += __shfl_xor(s1, m);
            }
            if (lead) {
                if (addb) { s0 += b10; s1 += b11; }
                float* o = out + ((size_t)(tglob * NE + e)) * 2;
                atomicAdd(o, s0);
                atomicAdd(o + 1, s1);
            }
        }
    }
}

// ---------------------------------------------------------------------------
extern "C" void kernel_launch(void* const* d_in, const int* in_sizes, int n_in,
                              void* d_out, int out_size, void* d_ws,
                              size_t ws_size, hipStream_t stream) {
    const float* piece = (const float*)d_in[0];
    const int* widx = (const int*)d_in[1];
    const int* tidx = (const int*)d_in[2];
    const int* eidx = (const int*)d_in[3];
    const float* W0 = (const float*)d_in[4];
    const float* b0 = (const float*)d_in[5];
    const float* W1 = (const float*)d_in[6];
    const float* b1 = (const float*)d_in[7];
    float* out = (float*)d_out;

    float* ws = (float*)d_ws;
    float* word = ws;                               // NB*NW*ND f32 (dead after span_mean)
    float* trig = word + (size_t)NB * NW * ND;      // NB*NT*ND f32
    float* ent = trig + (size_t)NB * NT * ND;       // NB*NE*ND f32
    float* pre_t = ent + (size_t)NB * NE * ND;      // NB*NT*NH f32
    float* pre_e = pre_t + (size_t)NB * NT * NH;    // NB*NE*NH f32
    __bf16* W0pre = (__bf16*)word;                  // 5*32*IMGP bf16 (aliases dead word)
    __bf16* W0pair = W0pre + (size_t)5 * 32 * IMGP; // 5*16*IMGQ bf16

    hipMemsetAsync(d_out, 0, (size_t)out_size * sizeof(float), stream);

    word_mean_kernel<<<NB * NW, 256, 0, stream>>>(piece, widx, word);
    span_mean_kernel<<<NB * (NT + NE), 256, 0, stream>>>(word, tidx, eidx, trig, ent);
    // word is dead from here on; swizzle overwrites it with W0pre/W0pair
    w0_swizzle_kernel<<<dim3(64, 5), 256, 0, stream>>>(W0, W0pre, W0pair);
    pre_mfma_kernel<<<dim3(24, 10), 64, 0, stream>>>(trig, ent, W0pre, pre_t, pre_e);
    pair_mfma_kernel<<<dim3(16, 16, 5), 256, 0, stream>>>(
        trig, ent, W0pair, b0, pre_t, pre_e, W1, b1, out);
}

// Round 5
// 263.658 us; speedup vs baseline: 5.2545x; 1.0283x over previous
//
#include <hip/hip_runtime.h>
#include <cstddef>
#include <cstdint>

typedef float f32x4 __attribute__((ext_vector_type(4)));
typedef __bf16 bf16x8 __attribute__((ext_vector_type(8)));
typedef __bf16 bf16x4 __attribute__((ext_vector_type(4)));

constexpr int NB = 16;   // batch
constexpr int NP = 512;  // pieces
constexpr int ND = 1024; // dim
constexpr int NW = 400;  // words
constexpr int NT = 32;   // triggers
constexpr int NE = 64;   // entities
constexpr int NH = 600;  // hidden
// W0pre: [nc=5][kb=32] images (128n x 64k bf16, XOR-swizzled) for slices a,b.
// W0pair: [nc=5][it=16] images (128n x 128k bf16): chunks 0-7 = W0c k-slice,
//   chunks 8-15 = W0d k-slice; pos = (c&8) | ((c^(n&7))&7).
constexpr int IMGP = 128 * 64;   // W0pre image elems
constexpr int IMGQ = 128 * 128;  // W0pair image elems

__device__ inline bf16x8 pack8(float a0, float a1, float a2, float a3,
                               float a4, float a5, float a6, float a7) {
    bf16x8 v;
    v[0] = (__bf16)a0; v[1] = (__bf16)a1; v[2] = (__bf16)a2; v[3] = (__bf16)a3;
    v[4] = (__bf16)a4; v[5] = (__bf16)a5; v[6] = (__bf16)a6; v[7] = (__bf16)a7;
    return v;
}

__device__ inline void dma16(const void* g, void* l) {
    __builtin_amdgcn_global_load_lds(
        (const __attribute__((address_space(1))) uint32_t*)g,
        (__attribute__((address_space(3))) uint32_t*)l, 16, 0, 0);
}

__device__ inline float bflo(uint32_t d) {
    union { uint32_t u; float f; } c; c.u = d << 16; return c.f;
}
__device__ inline float bfhi(uint32_t d) {
    union { uint32_t u; float f; } c; c.u = d & 0xFFFF0000u; return c.f;
}

// ---------------------------------------------------------------------------
// Kernel 1: word means over piece intervals. grid = NB*NW, block = 256.
__global__ __launch_bounds__(256) void word_mean_kernel(
    const float* __restrict__ piece, const int* __restrict__ widx,
    float* __restrict__ word) {
    int bw = blockIdx.x;
    int b = bw / NW;
    int s = widx[bw * 2], e = widx[bw * 2 + 1];
    int col = threadIdx.x * 4;
    const float* base = piece + (size_t)b * NP * ND + col;
    float4 acc = make_float4(0.f, 0.f, 0.f, 0.f);
    for (int r = s; r < e; ++r) {
        float4 v = *(const float4*)(base + (size_t)r * ND);
        acc.x += v.x; acc.y += v.y; acc.z += v.z; acc.w += v.w;
    }
    float inv = 1.0f / (float)(e - s);
    acc.x *= inv; acc.y *= inv; acc.z *= inv; acc.w *= inv;
    *(float4*)(word + (size_t)bw * ND + col) = acc;
}

// ---------------------------------------------------------------------------
// Kernel 2: span means over word intervals (trig + ent in one grid).
__global__ __launch_bounds__(256) void span_mean_kernel(
    const float* __restrict__ word, const int* __restrict__ tidx,
    const int* __restrict__ eidx, float* __restrict__ trig,
    float* __restrict__ ent) {
    int id = blockIdx.x;
    const int* idx;
    float* out;
    int b;
    if (id < NB * NT) {
        b = id / NT; idx = tidx + id * 2; out = trig + (size_t)id * ND;
    } else {
        int id2 = id - NB * NT;
        b = id2 / NE; idx = eidx + id2 * 2; out = ent + (size_t)id2 * ND;
    }
    int s = idx[0], e = idx[1];
    int col = threadIdx.x * 4;
    const float* base = word + (size_t)b * NW * ND + col;
    float4 acc = make_float4(0.f, 0.f, 0.f, 0.f);
    for (int r = s; r < e; ++r) {
        float4 v = *(const float4*)(base + (size_t)r * ND);
        acc.x += v.x; acc.y += v.y; acc.z += v.z; acc.w += v.w;
    }
    float inv = 1.0f / (float)(e - s);
    acc.x *= inv; acc.y *= inv; acc.z *= inv; acc.w *= inv;
    *(float4*)(out + col) = acc;
}

// ---------------------------------------------------------------------------
// Kernel 3: W0 [4096][600] f32 -> swizzled bf16 images (W0pre + W0pair).
// grid = (kb=64, nc=5), block = 256.
__global__ __launch_bounds__(256) void w0_swizzle_kernel(
    const float* __restrict__ W0, __bf16* __restrict__ W0pre,
    __bf16* __restrict__ W0pair) {
    __shared__ float T[64][132];   // [k local][n local], padded
    int kb = blockIdx.x, nc = blockIdx.y;
    int t = threadIdx.x;
    {
        int kl = t >> 2;
        int n0 = (t & 3) * 32;
        int kg = kb * 64 + kl;
        const float* src = W0 + (size_t)kg * NH + nc * 128 + n0;
#pragma unroll
        for (int g = 0; g < 8; ++g) {
            int n = nc * 128 + n0 + g * 4;
            float4 v = (n < NH) ? *(const float4*)(src + g * 4)
                                : make_float4(0.f, 0.f, 0.f, 0.f);
            *(float4*)&T[kl][n0 + g * 4] = v;
        }
    }
    __syncthreads();
#pragma unroll
    for (int s = 0; s < 4; ++s) {
        int idx = t * 4 + s;       // (row=n-local, c=k-chunk)
        int row = idx >> 3, c = idx & 7;
        bf16x8 v = pack8(T[c * 8 + 0][row], T[c * 8 + 1][row],
                         T[c * 8 + 2][row], T[c * 8 + 3][row],
                         T[c * 8 + 4][row], T[c * 8 + 5][row],
                         T[c * 8 + 6][row], T[c * 8 + 7][row]);
        if (kb < 32) {
            __bf16* img = W0pre + ((size_t)nc * 32 + kb) * IMGP;
            *(bf16x8*)&img[row * 64 + ((c ^ (row & 7)) << 3)] = v;
        } else {
            bool isD = kb >= 48;
            int it = kb - (isD ? 48 : 32);
            __bf16* img = W0pair + ((size_t)nc * 16 + it) * IMGQ;
            int pos = ((c ^ (row & 7)) & 7) | (isD ? 8 : 0);
            *(bf16x8*)&img[row * 128 + (pos << 3)] = v;
        }
    }
}

// ---------------------------------------------------------------------------
// Kernel 4: pre-projection GEMMs, 64x64 tiles, 1 wave per block.
// grid = (24 mtile [0..7 trig, 8..23 ent], 10 ntile), block = 64.
__global__ __launch_bounds__(64) void pre_mfma_kernel(
    const float* __restrict__ trig, const float* __restrict__ ent,
    const __bf16* __restrict__ W0pre, float* __restrict__ pre_t,
    float* __restrict__ pre_e) {
    __shared__ __bf16 As[64 * 64];
    __shared__ __bf16 Bs[64 * 64];
    int mt8 = blockIdx.x, ntile = blockIdx.y;
    const float* A;
    float* C;
    int kbofs, mbase;
    if (mt8 < 8) { A = trig; C = pre_t; kbofs = 0;  mbase = mt8 * 64; }
    else         { A = ent;  C = pre_e; kbofs = 16; mbase = (mt8 - 8) * 64; }
    int lane = threadIdx.x;
    int q = lane >> 4, l15 = lane & 15, sa = l15 & 7;
    int nc = ntile >> 1, half = ntile & 1;
    const __bf16* imgbase =
        W0pre + ((size_t)nc * 32 + kbofs) * IMGP + half * 4096;
    f32x4 acc[4][4] = {};

    for (int it = 0; it < 16; ++it) {
        __syncthreads();
        const __bf16* img = imgbase + (size_t)it * IMGP;
#pragma unroll
        for (int i = 0; i < 8; ++i)
            dma16(img + i * 512 + lane * 8, (__bf16*)Bs + i * 512);
#pragma unroll
        for (int s = 0; s < 8; ++s) {
            int L = s * 64 + lane;
            int r = L >> 3, c = L & 7;
            const float* ar = A + (size_t)(mbase + r) * ND + it * 64 + c * 8;
            float4 a0 = *(const float4*)ar, a1 = *(const float4*)(ar + 4);
            *(bf16x8*)&As[r * 64 + ((c ^ (r & 7)) << 3)] =
                pack8(a0.x, a0.y, a0.z, a0.w, a1.x, a1.y, a1.z, a1.w);
        }
        __syncthreads();
#pragma unroll
        for (int ks = 0; ks < 2; ++ks) {
            int coff = ((q ^ sa) ^ (ks << 2)) << 3;
            bf16x8 af[4];
#pragma unroll
            for (int mt = 0; mt < 4; ++mt)
                af[mt] = *(const bf16x8*)&As[(16 * mt + l15) * 64 + coff];
#pragma unroll
            for (int nt = 0; nt < 4; ++nt) {
                bf16x8 bf = *(const bf16x8*)&Bs[(16 * nt + l15) * 64 + coff];
#pragma unroll
                for (int mt = 0; mt < 4; ++mt)
                    acc[mt][nt] = __builtin_amdgcn_mfma_f32_16x16x32_bf16(
                        af[mt], bf, acc[mt][nt], 0, 0, 0);
            }
        }
    }
#pragma unroll
    for (int mt = 0; mt < 4; ++mt)
#pragma unroll
        for (int r = 0; r < 4; ++r) {
            float* crow = C + (size_t)(mbase + 16 * mt + 4 * q + r) * NH;
#pragma unroll
            for (int nt = 0; nt < 4; ++nt) {
                int n = ntile * 64 + 16 * nt + l15;
                if (n < NH) crow[n] = acc[mt][nt][r];
            }
        }
}

// ---------------------------------------------------------------------------
// Kernel 5: pairwise GEMM + fused FFN epilogue. M=64 (ONE trigger x 64
// entities), N=128, BK=128 (product|absdiff fused). LDS 50 KB -> 3 blocks/CU.
// grid = (16 b, 32 t, 5 nc), block = 256 (4 waves, 2x2 tile of 32e x 64n).
__global__ __launch_bounds__(256, 3) void pair_mfma_kernel(
    const float* __restrict__ trig, const float* __restrict__ ent,
    const __bf16* __restrict__ W0pair, const float* __restrict__ b0,
    const float* __restrict__ pre_t, const float* __restrict__ pre_e,
    const float* __restrict__ W1, const float* __restrict__ b1,
    float* __restrict__ out) {
    __shared__ __bf16 Xs[64 * 128];    // 16 KB: 64 e-rows x [prod64|diff64]
    __shared__ __bf16 Bs[128 * 128];   // 32 KB
    __shared__ __bf16 Ts[1024];        // 2 KB trigger row (bf16)
    int b = blockIdx.x, t = blockIdx.y, nc = blockIdx.z;
    int tid = threadIdx.x;
    int lane = tid & 63, w = tid >> 6, rw = w & 1, cw = w >> 1;
    int q = lane >> 4, l15 = lane & 15, sa = l15 & 7;
    int xe = tid >> 2, c4 = tid & 3, e7 = xe & 7;
    const float* trow = trig + (size_t)(b * NT + t) * ND;
    const float* erow = ent + (size_t)(b * NE + xe) * ND;
    const __bf16* imgbase = W0pair + (size_t)nc * 16 * IMGQ;
    f32x4 acc[2][4] = {};
    float4 ef4[4];

    auto dma_b = [&](int it) {
        const __bf16* img = imgbase + (size_t)it * IMGQ + w * 4096;
        __bf16* lds = (__bf16*)Bs + w * 4096;
#pragma unroll
        for (int i = 0; i < 8; ++i)
            dma16(img + i * 512 + lane * 8, lds + i * 512);
    };
    auto load_e = [&](int it) {
        const float* er = erow + it * 64 + c4 * 16;
#pragma unroll
        for (int i = 0; i < 4; ++i) ef4[i] = *(const float4*)(er + i * 4);
    };
    auto write_x = [&](int it) {
        const uint32_t* tpr = (const uint32_t*)&Ts[it * 64 + c4 * 16];
        int base0 = xe * 128;
#pragma unroll
        for (int g = 0; g < 2; ++g) {
            float ef[8];
            ef[0] = ef4[2 * g].x; ef[1] = ef4[2 * g].y;
            ef[2] = ef4[2 * g].z; ef[3] = ef4[2 * g].w;
            ef[4] = ef4[2 * g + 1].x; ef[5] = ef4[2 * g + 1].y;
            ef[6] = ef4[2 * g + 1].z; ef[7] = ef4[2 * g + 1].w;
            float tf[8];
#pragma unroll
            for (int d = 0; d < 4; ++d) {
                uint32_t dv = tpr[g * 4 + d];
                tf[2 * d] = bflo(dv); tf[2 * d + 1] = bfhi(dv);
            }
            int pos = (((2 * c4 + g) ^ e7) << 3);
            *(bf16x8*)&Xs[base0 + pos] = pack8(
                tf[0] * ef[0], tf[1] * ef[1], tf[2] * ef[2], tf[3] * ef[3],
                tf[4] * ef[4], tf[5] * ef[5], tf[6] * ef[6], tf[7] * ef[7]);
            *(bf16x8*)&Xs[base0 + pos + 64] = pack8(
                fabsf(tf[0] - ef[0]), fabsf(tf[1] - ef[1]),
                fabsf(tf[2] - ef[2]), fabsf(tf[3] - ef[3]),
                fabsf(tf[4] - ef[4]), fabsf(tf[5] - ef[5]),
                fabsf(tf[6] - ef[6]), fabsf(tf[7] - ef[7]));
        }
    };
    auto mfma_tile = [&]() {
#pragma unroll
        for (int ks = 0; ks < 4; ++ks) {
            int coff = (((ks & 2) << 2) | ((q | ((ks & 1) << 2)) ^ sa)) << 3;
            bf16x8 af[2];
#pragma unroll
            for (int mt = 0; mt < 2; ++mt)
                af[mt] =
                    *(const bf16x8*)&Xs[(32 * rw + 16 * mt + l15) * 128 + coff];
#pragma unroll
            for (int nt = 0; nt < 4; ++nt) {
                bf16x8 bf =
                    *(const bf16x8*)&Bs[(64 * cw + 16 * nt + l15) * 128 + coff];
#pragma unroll
                for (int mt = 0; mt < 2; ++mt)
                    acc[mt][nt] = __builtin_amdgcn_mfma_f32_16x16x32_bf16(
                        af[mt], bf, acc[mt][nt], 0, 0, 0);
            }
        }
    };

    // --- preamble: trigger row -> LDS bf16; first tiles in flight ---
    {
        int k0 = tid * 4;
        float4 va = *(const float4*)(trow + k0);
        bf16x4 pa;
        pa[0] = (__bf16)va.x; pa[1] = (__bf16)va.y;
        pa[2] = (__bf16)va.z; pa[3] = (__bf16)va.w;
        *(bf16x4*)&Ts[k0] = pa;
    }
    dma_b(0);
    load_e(0);
    __syncthreads();           // Ts visible (DMA 0 also drains; harmless)
    write_x(0);
    __syncthreads();           // X(0), B(0) ready

    for (int it = 0; it < 16; ++it) {
        if (it < 15) load_e(it + 1);   // prefetch; latency hides under MFMA
        mfma_tile();
        __syncthreads();               // fragment reads done; buffers free
        if (it < 15) {
            dma_b(it + 1);
            write_x(it + 1);
            __syncthreads();           // X/B(it+1) ready (DMA drained)
        }
    }

    // --- epilogue: h = relu(acc + pre_t + pre_e + b0); out += h @ W1 ---
    int tglob = b * NT + t;
    const float* preT = pre_t + (size_t)tglob * NH;
    float w10[4], w11[4], b0v[4], ptv[4];
    int nbase = nc * 128 + 64 * cw + l15;
#pragma unroll
    for (int nt = 0; nt < 4; ++nt) {
        int n = nbase + 16 * nt;
        bool v = n < NH;
        w10[nt] = v ? W1[2 * n] : 0.f;
        w11[nt] = v ? W1[2 * n + 1] : 0.f;
        b0v[nt] = v ? b0[n] : 0.f;
        ptv[nt] = v ? preT[n] : 0.f;
    }
    float b10 = b1[0], b11 = b1[1];
    bool lead = (l15 == 0);
    bool addb = (nc == 0) && (cw == 0);
#pragma unroll
    for (int mt = 0; mt < 2; ++mt) {
#pragma unroll
        for (int r = 0; r < 4; ++r) {
            int e = 32 * rw + 16 * mt + 4 * q + r;
            const float* preE = pre_e + (size_t)(b * NE + e) * NH;
            float s0 = 0.f, s1 = 0.f;
#pragma unroll
            for (int nt = 0; nt < 4; ++nt) {
                int n = nbase + 16 * nt;
                float pe = (n < NH) ? preE[n] : 0.f;
                float h = acc[mt][nt][r] + ptv[nt] + pe + b0v[nt];
                h = fmaxf(h, 0.f);
                s0 += h * w10[nt];
                s1 += h * w11[nt];
            }
#pragma unroll
            for (int m = 8; m >= 1; m >>= 1) {
                s0 += __shfl_xor(s0, m);
                s1 += __shfl_xor(s1, m);
            }
            if (lead) {
                if (addb) { s0 += b10; s1 += b11; }
                float* o = out + ((size_t)(tglob * NE + e)) * 2;
                atomicAdd(o, s0);
                atomicAdd(o + 1, s1);
            }
        }
    }
}

// ---------------------------------------------------------------------------
extern "C" void kernel_launch(void* const* d_in, const int* in_sizes, int n_in,
                              void* d_out, int out_size, void* d_ws,
                              size_t ws_size, hipStream_t stream) {
    const float* piece = (const float*)d_in[0];
    const int* widx = (const int*)d_in[1];
    const int* tidx = (const int*)d_in[2];
    const int* eidx = (const int*)d_in[3];
    const float* W0 = (const float*)d_in[4];
    const float* b0 = (const float*)d_in[5];
    const float* W1 = (const float*)d_in[6];
    const float* b1 = (const float*)d_in[7];
    float* out = (float*)d_out;

    float* ws = (float*)d_ws;
    float* word = ws;                               // NB*NW*ND f32 (dead after span_mean)
    float* trig = word + (size_t)NB * NW * ND;      // NB*NT*ND f32
    float* ent = trig + (size_t)NB * NT * ND;       // NB*NE*ND f32
    float* pre_t = ent + (size_t)NB * NE * ND;      // NB*NT*NH f32
    float* pre_e = pre_t + (size_t)NB * NT * NH;    // NB*NE*NH f32
    __bf16* W0pre = (__bf16*)word;                  // 5*32*IMGP bf16 (aliases dead word)
    __bf16* W0pair = W0pre + (size_t)5 * 32 * IMGP; // 5*16*IMGQ bf16

    hipMemsetAsync(d_out, 0, (size_t)out_size * sizeof(float), stream);

    word_mean_kernel<<<NB * NW, 256, 0, stream>>>(piece, widx, word);
    span_mean_kernel<<<NB * (NT + NE), 256, 0, stream>>>(word, tidx, eidx, trig, ent);
    // word is dead from here on; swizzle overwrites it with W0pre/W0pair
    w0_swizzle_kernel<<<dim3(64, 5), 256, 0, stream>>>(W0, W0pre, W0pair);
    pre_mfma_kernel<<<dim3(24, 10), 64, 0, stream>>>(trig, ent, W0pre, pre_t, pre_e);
    pair_mfma_kernel<<<dim3(16, 32, 5), 256, 0, stream>>>(
        trig, ent, W0pair, b0, pre_t, pre_e, W1, b1, out);
}

// Round 6
// 226.316 us; speedup vs baseline: 6.1215x; 1.1650x over previous
//
#include <hip/hip_runtime.h>
#include <cstddef>
#include <cstdint>

typedef float f32x4 __attribute__((ext_vector_type(4)));
typedef __bf16 bf16x8 __attribute__((ext_vector_type(8)));
typedef __bf16 bf16x4 __attribute__((ext_vector_type(4)));

constexpr int NB = 16;   // batch
constexpr int NP = 512;  // pieces
constexpr int ND = 1024; // dim
constexpr int NW = 400;  // words
constexpr int NT = 32;   // triggers
constexpr int NE = 64;   // entities
constexpr int NH = 600;  // hidden
// W0pre: [nc=5][kb=32] images (128n x 64k bf16, XOR swizzle) - pre GEMM slices.
// W0pair: [nc=2][it=32] images (320n x 64c bf16, ROTATION swizzle):
//   chunk c<4 -> W0c k-slice it*32+c*8+j ; c>=4 -> W0d k-slice it*32+(c-4)*8+j
//   stored at row r, slot ((c + (r&7)) & 7), zero-padded for n >= 600.
constexpr int IMGP = 128 * 64;   // W0pre image elems
constexpr int IMGQ = 320 * 64;   // W0pair image elems

__device__ inline bf16x8 pack8(float a0, float a1, float a2, float a3,
                               float a4, float a5, float a6, float a7) {
    bf16x8 v;
    v[0] = (__bf16)a0; v[1] = (__bf16)a1; v[2] = (__bf16)a2; v[3] = (__bf16)a3;
    v[4] = (__bf16)a4; v[5] = (__bf16)a5; v[6] = (__bf16)a6; v[7] = (__bf16)a7;
    return v;
}

__device__ inline void dma16(const void* g, void* l) {
    __builtin_amdgcn_global_load_lds(
        (const __attribute__((address_space(1))) uint32_t*)g,
        (__attribute__((address_space(3))) uint32_t*)l, 16, 0, 0);
}

// ---------------------------------------------------------------------------
// Kernel 1: word means over piece intervals. grid = NB*NW, block = 256.
__global__ __launch_bounds__(256) void word_mean_kernel(
    const float* __restrict__ piece, const int* __restrict__ widx,
    float* __restrict__ word) {
    int bw = blockIdx.x;
    int b = bw / NW;
    int s = widx[bw * 2], e = widx[bw * 2 + 1];
    int col = threadIdx.x * 4;
    const float* base = piece + (size_t)b * NP * ND + col;
    float4 acc = make_float4(0.f, 0.f, 0.f, 0.f);
    for (int r = s; r < e; ++r) {
        float4 v = *(const float4*)(base + (size_t)r * ND);
        acc.x += v.x; acc.y += v.y; acc.z += v.z; acc.w += v.w;
    }
    float inv = 1.0f / (float)(e - s);
    acc.x *= inv; acc.y *= inv; acc.z *= inv; acc.w *= inv;
    *(float4*)(word + (size_t)bw * ND + col) = acc;
}

// ---------------------------------------------------------------------------
// Kernel 2: span means over word intervals (trig + ent in one grid).
__global__ __launch_bounds__(256) void span_mean_kernel(
    const float* __restrict__ word, const int* __restrict__ tidx,
    const int* __restrict__ eidx, float* __restrict__ trig,
    float* __restrict__ ent) {
    int id = blockIdx.x;
    const int* idx;
    float* out;
    int b;
    if (id < NB * NT) {
        b = id / NT; idx = tidx + id * 2; out = trig + (size_t)id * ND;
    } else {
        int id2 = id - NB * NT;
        b = id2 / NE; idx = eidx + id2 * 2; out = ent + (size_t)id2 * ND;
    }
    int s = idx[0], e = idx[1];
    int col = threadIdx.x * 4;
    const float* base = word + (size_t)b * NW * ND + col;
    float4 acc = make_float4(0.f, 0.f, 0.f, 0.f);
    for (int r = s; r < e; ++r) {
        float4 v = *(const float4*)(base + (size_t)r * ND);
        acc.x += v.x; acc.y += v.y; acc.z += v.z; acc.w += v.w;
    }
    float inv = 1.0f / (float)(e - s);
    acc.x *= inv; acc.y *= inv; acc.z *= inv; acc.w *= inv;
    *(float4*)(out + col) = acc;
}

// ---------------------------------------------------------------------------
// Kernel 3a: W0 slices a,b -> W0pre images (XOR swizzle, unchanged layout).
// grid = (kb=32, nc=5), block = 256.
__global__ __launch_bounds__(256) void w0_swizzle_kernel(
    const float* __restrict__ W0, __bf16* __restrict__ W0pre) {
    __shared__ float T[64][132];
    int kb = blockIdx.x, nc = blockIdx.y;
    int t = threadIdx.x;
    {
        int kl = t >> 2;
        int n0 = (t & 3) * 32;
        int kg = kb * 64 + kl;
        const float* src = W0 + (size_t)kg * NH + nc * 128 + n0;
#pragma unroll
        for (int g = 0; g < 8; ++g) {
            int n = nc * 128 + n0 + g * 4;
            float4 v = (n < NH) ? *(const float4*)(src + g * 4)
                                : make_float4(0.f, 0.f, 0.f, 0.f);
            *(float4*)&T[kl][n0 + g * 4] = v;
        }
    }
    __syncthreads();
#pragma unroll
    for (int s = 0; s < 4; ++s) {
        int idx = t * 4 + s;
        int row = idx >> 3, c = idx & 7;
        bf16x8 v = pack8(T[c * 8 + 0][row], T[c * 8 + 1][row],
                         T[c * 8 + 2][row], T[c * 8 + 3][row],
                         T[c * 8 + 4][row], T[c * 8 + 5][row],
                         T[c * 8 + 6][row], T[c * 8 + 7][row]);
        __bf16* img = W0pre + ((size_t)nc * 32 + kb) * IMGP;
        *(bf16x8*)&img[row * 64 + ((c ^ (row & 7)) << 3)] = v;
    }
}

// ---------------------------------------------------------------------------
// Kernel 3b: W0 slices c,d -> W0pair images (rotation swizzle).
// grid = (it=32, nc=2, quarter=4), block = 256. Each block: 80 n-rows.
__global__ __launch_bounds__(256) void w0_pair_kernel(
    const float* __restrict__ W0, __bf16* __restrict__ W0pair) {
    __shared__ float T[64][84];   // [kidx = c*8+j][n-local 0..79]
    int it = blockIdx.x, nc = blockIdx.y, zz = blockIdx.z;
    int tid = threadIdx.x;
    {
        int kidx = tid >> 2, npart = tid & 3;   // 20 n per thread
        int korig = 2048 + (kidx >> 5) * 1024 + it * 32 + (kidx & 31);
        const float* src = W0 + (size_t)korig * NH;
        int nbase = nc * 320 + zz * 80 + npart * 20;
#pragma unroll
        for (int g = 0; g < 5; ++g) {
            int n = nbase + g * 4;
            float4 v = (n < NH) ? *(const float4*)(src + n)
                                : make_float4(0.f, 0.f, 0.f, 0.f);
            *(float4*)&T[kidx][npart * 20 + g * 4] = v;
        }
    }
    __syncthreads();
    __bf16* img = W0pair + ((size_t)nc * 32 + it) * IMGQ + (size_t)zz * 80 * 64;
#pragma unroll
    for (int s = 0; s < 3; ++s) {
        int idx = s * 256 + tid;
        if (idx < 640) {
            int r = idx >> 3, c = idx & 7;
            bf16x8 v = pack8(T[c * 8 + 0][r], T[c * 8 + 1][r],
                             T[c * 8 + 2][r], T[c * 8 + 3][r],
                             T[c * 8 + 4][r], T[c * 8 + 5][r],
                             T[c * 8 + 6][r], T[c * 8 + 7][r]);
            int slot = (c + (r & 7)) & 7;
            *(bf16x8*)&img[r * 64 + slot * 8] = v;
        }
    }
}

// ---------------------------------------------------------------------------
// Kernel 4: pre-projection GEMMs, 64x64 tiles, 1 wave per block.
// grid = (24 mtile [0..7 trig, 8..23 ent], 10 ntile), block = 64.
__global__ __launch_bounds__(64) void pre_mfma_kernel(
    const float* __restrict__ trig, const float* __restrict__ ent,
    const __bf16* __restrict__ W0pre, float* __restrict__ pre_t,
    float* __restrict__ pre_e) {
    __shared__ __bf16 As[64 * 64];
    __shared__ __bf16 Bs[64 * 64];
    int mt8 = blockIdx.x, ntile = blockIdx.y;
    const float* A;
    float* C;
    int kbofs, mbase;
    if (mt8 < 8) { A = trig; C = pre_t; kbofs = 0;  mbase = mt8 * 64; }
    else         { A = ent;  C = pre_e; kbofs = 16; mbase = (mt8 - 8) * 64; }
    int lane = threadIdx.x;
    int q = lane >> 4, l15 = lane & 15, sa = l15 & 7;
    int nc = ntile >> 1, half = ntile & 1;
    const __bf16* imgbase =
        W0pre + ((size_t)nc * 32 + kbofs) * IMGP + half * 4096;
    f32x4 acc[4][4] = {};

    for (int it = 0; it < 16; ++it) {
        __syncthreads();
        const __bf16* img = imgbase + (size_t)it * IMGP;
#pragma unroll
        for (int i = 0; i < 8; ++i)
            dma16(img + i * 512 + lane * 8, (__bf16*)Bs + i * 512);
#pragma unroll
        for (int s = 0; s < 8; ++s) {
            int L = s * 64 + lane;
            int r = L >> 3, c = L & 7;
            const float* ar = A + (size_t)(mbase + r) * ND + it * 64 + c * 8;
            float4 a0 = *(const float4*)ar, a1 = *(const float4*)(ar + 4);
            *(bf16x8*)&As[r * 64 + ((c ^ (r & 7)) << 3)] =
                pack8(a0.x, a0.y, a0.z, a0.w, a1.x, a1.y, a1.z, a1.w);
        }
        __syncthreads();
#pragma unroll
        for (int ks = 0; ks < 2; ++ks) {
            int coff = ((q ^ sa) ^ (ks << 2)) << 3;
            bf16x8 af[4];
#pragma unroll
            for (int mt = 0; mt < 4; ++mt)
                af[mt] = *(const bf16x8*)&As[(16 * mt + l15) * 64 + coff];
#pragma unroll
            for (int nt = 0; nt < 4; ++nt) {
                bf16x8 bf = *(const bf16x8*)&Bs[(16 * nt + l15) * 64 + coff];
#pragma unroll
                for (int mt = 0; mt < 4; ++mt)
                    acc[mt][nt] = __builtin_amdgcn_mfma_f32_16x16x32_bf16(
                        af[mt], bf, acc[mt][nt], 0, 0, 0);
            }
        }
    }
#pragma unroll
    for (int mt = 0; mt < 4; ++mt)
#pragma unroll
        for (int r = 0; r < 4; ++r) {
            float* crow = C + (size_t)(mbase + 16 * mt + 4 * q + r) * NH;
#pragma unroll
            for (int nt = 0; nt < 4; ++nt) {
                int n = ntile * 64 + 16 * nt + l15;
                if (n < NH) crow[n] = acc[mt][nt][r];
            }
        }
}

// ---------------------------------------------------------------------------
// Kernel 5: pairwise GEMM + fused FFN epilogue.
// M=128 (2 triggers x 64 e), N=320, kreal=32/iter (Xcols 64 = prod|diff).
// Wave tile 64x160 (mt=4, nt=10). LDS 60 KB -> 2 blocks/CU.
// grid = (16 b, 16 tp, 2 nc), block = 256.
__global__ __launch_bounds__(256, 2) void pair_mfma_kernel(
    const float* __restrict__ trig, const float* __restrict__ ent,
    const __bf16* __restrict__ W0pair, const float* __restrict__ b0,
    const float* __restrict__ pre_t, const float* __restrict__ pre_e,
    const float* __restrict__ W1, const float* __restrict__ b1,
    float* __restrict__ out) {
    __shared__ __bf16 Xs[128 * 64];    // 16 KB: rows 0-63 t0 x e, 64-127 t1 x e
    __shared__ __bf16 Bs[320 * 64];    // 40 KB
    __shared__ __bf16 Ts[2 * 1024];    // 4 KB trigger rows (bf16)
    int b = blockIdx.x, tp = blockIdx.y, nc = blockIdx.z;
    int tid = threadIdx.x;
    int lane = tid & 63, w = tid >> 6, rw = w & 1, cw = w >> 1;
    int q = lane >> 4, l15 = lane & 15, s7 = l15 & 7;
    int xrow = tid >> 1, xh = tid & 1;       // X staging: row 0..127, k-half
    int xr7 = xrow & 7;
    const float* t0row = trig + (size_t)(b * NT + tp * 2 + 0) * ND;
    const float* t1row = trig + (size_t)(b * NT + tp * 2 + 1) * ND;
    const float* erow = ent + (size_t)(b * NE + (xrow & 63)) * ND;
    const __bf16* imgbase = W0pair + (size_t)nc * 32 * IMGQ;
    f32x4 acc[4][10] = {};
    float4 ef4[4];

    auto dma_b = [&](int it) {
        const __bf16* img = imgbase + (size_t)it * IMGQ + w * 5120;
        __bf16* lds = (__bf16*)Bs + w * 5120;
#pragma unroll
        for (int i = 0; i < 10; ++i)
            dma16(img + i * 512 + lane * 8, lds + i * 512);
    };
    auto load_e = [&](int it) {
        const float* er = erow + it * 32 + xh * 16;
#pragma unroll
        for (int i = 0; i < 4; ++i) ef4[i] = *(const float4*)(er + i * 4);
    };
    auto write_x = [&](int it) {
        const __bf16* tsrc = &Ts[(xrow >> 6) * 1024 + it * 32 + xh * 16];
        bf16x8 tlo = *(const bf16x8*)tsrc;
        bf16x8 thi = *(const bf16x8*)(tsrc + 8);
        float tf[16], ef[16];
#pragma unroll
        for (int j = 0; j < 8; ++j) { tf[j] = (float)tlo[j]; tf[8 + j] = (float)thi[j]; }
        ef[0] = ef4[0].x; ef[1] = ef4[0].y; ef[2] = ef4[0].z; ef[3] = ef4[0].w;
        ef[4] = ef4[1].x; ef[5] = ef4[1].y; ef[6] = ef4[1].z; ef[7] = ef4[1].w;
        ef[8] = ef4[2].x; ef[9] = ef4[2].y; ef[10] = ef4[2].z; ef[11] = ef4[2].w;
        ef[12] = ef4[3].x; ef[13] = ef4[3].y; ef[14] = ef4[3].z; ef[15] = ef4[3].w;
        int base = xrow * 64;
        // prod chunks 2*xh, 2*xh+1 ; diff chunks +4 ; slot = (c + r&7) & 7
        int sp0 = ((2 * xh + 0 + xr7) & 7) * 8;
        int sp1 = ((2 * xh + 1 + xr7) & 7) * 8;
        int sd0 = ((2 * xh + 4 + xr7) & 7) * 8;
        int sd1 = ((2 * xh + 5 + xr7) & 7) * 8;
        *(bf16x8*)&Xs[base + sp0] = pack8(
            tf[0] * ef[0], tf[1] * ef[1], tf[2] * ef[2], tf[3] * ef[3],
            tf[4] * ef[4], tf[5] * ef[5], tf[6] * ef[6], tf[7] * ef[7]);
        *(bf16x8*)&Xs[base + sp1] = pack8(
            tf[8] * ef[8], tf[9] * ef[9], tf[10] * ef[10], tf[11] * ef[11],
            tf[12] * ef[12], tf[13] * ef[13], tf[14] * ef[14], tf[15] * ef[15]);
        *(bf16x8*)&Xs[base + sd0] = pack8(
            fabsf(tf[0] - ef[0]), fabsf(tf[1] - ef[1]),
            fabsf(tf[2] - ef[2]), fabsf(tf[3] - ef[3]),
            fabsf(tf[4] - ef[4]), fabsf(tf[5] - ef[5]),
            fabsf(tf[6] - ef[6]), fabsf(tf[7] - ef[7]));
        *(bf16x8*)&Xs[base + sd1] = pack8(
            fabsf(tf[8] - ef[8]), fabsf(tf[9] - ef[9]),
            fabsf(tf[10] - ef[10]), fabsf(tf[11] - ef[11]),
            fabsf(tf[12] - ef[12]), fabsf(tf[13] - ef[13]),
            fabsf(tf[14] - ef[14]), fabsf(tf[15] - ef[15]));
    };
    auto mfma_tile = [&]() {
#pragma unroll
        for (int ks = 0; ks < 2; ++ks) {
            int slot = ((4 * ks + q + s7) & 7) * 8;
            bf16x8 af[4];
#pragma unroll
            for (int mt = 0; mt < 4; ++mt)
                af[mt] = *(const bf16x8*)&Xs[(64 * rw + 16 * mt + l15) * 64 + slot];
#pragma unroll
            for (int nt = 0; nt < 10; ++nt) {
                bf16x8 bfv =
                    *(const bf16x8*)&Bs[(160 * cw + 16 * nt + l15) * 64 + slot];
#pragma unroll
                for (int mt = 0; mt < 4; ++mt)
                    acc[mt][nt] = __builtin_amdgcn_mfma_f32_16x16x32_bf16(
                        af[mt], bfv, acc[mt][nt], 0, 0, 0);
            }
        }
    };

    // --- preamble: trigger rows -> LDS bf16; first tile in flight ---
    {
        int k0 = tid * 4;
        float4 va = *(const float4*)(t0row + k0);
        float4 vb = *(const float4*)(t1row + k0);
        bf16x4 pa, pb;
        pa[0] = (__bf16)va.x; pa[1] = (__bf16)va.y;
        pa[2] = (__bf16)va.z; pa[3] = (__bf16)va.w;
        pb[0] = (__bf16)vb.x; pb[1] = (__bf16)vb.y;
        pb[2] = (__bf16)vb.z; pb[3] = (__bf16)vb.w;
        *(bf16x4*)&Ts[k0] = pa;
        *(bf16x4*)&Ts[1024 + k0] = pb;
    }
    dma_b(0);
    load_e(0);
    __syncthreads();           // Ts visible, DMA(0) drained
    write_x(0);
    __syncthreads();           // X(0), B(0) ready

    for (int it = 0; it < 32; ++it) {
        if (it < 31) load_e(it + 1);   // prefetch; hides under MFMA
        mfma_tile();
        __syncthreads();               // buffer reads done
        if (it < 31) {
            dma_b(it + 1);
            write_x(it + 1);
            __syncthreads();           // X/B(it+1) ready (DMA drained)
        }
    }

    // --- epilogue: h = relu(acc + pre_t + pre_e + b0); out += h @ W1 ---
    int tglob = b * NT + tp * 2 + rw;
    const float* preT = pre_t + (size_t)tglob * NH;
    float w10[10], w11[10], b0v[10], ptv[10];
    int nbase = nc * 320 + 160 * cw + l15;
#pragma unroll
    for (int nt = 0; nt < 10; ++nt) {
        int n = nbase + 16 * nt;
        bool v = n < NH;
        w10[nt] = v ? W1[2 * n] : 0.f;
        w11[nt] = v ? W1[2 * n + 1] : 0.f;
        b0v[nt] = v ? b0[n] : 0.f;
        ptv[nt] = v ? preT[n] : 0.f;
    }
    float b10 = b1[0], b11 = b1[1];
    bool lead = (l15 == 0);
    bool addb = (nc == 0) && (cw == 0);
#pragma unroll
    for (int mt = 0; mt < 4; ++mt) {
#pragma unroll
        for (int r = 0; r < 4; ++r) {
            int e = 16 * mt + 4 * q + r;
            const float* preE = pre_e + (size_t)(b * NE + e) * NH;
            float s0 = 0.f, s1 = 0.f;
#pragma unroll
            for (int nt = 0; nt < 10; ++nt) {
                int n = nbase + 16 * nt;
                float pe = (n < NH) ? preE[n] : 0.f;
                float h = acc[mt][nt][r] + ptv[nt] + pe + b0v[nt];
                h = fmaxf(h, 0.f);
                s0 += h * w10[nt];
                s1 += h * w11[nt];
            }
#pragma unroll
            for (int m = 8; m >= 1; m >>= 1) {
                s0 += __shfl_xor(s0, m);
                s1 += __shfl_xor(s1, m);
            }
            if (lead) {
                if (addb) { s0 += b10; s1 += b11; }
                float* o = out + ((size_t)(tglob * NE + e)) * 2;
                atomicAdd(o, s0);
                atomicAdd(o + 1, s1);
            }
        }
    }
}

// ---------------------------------------------------------------------------
extern "C" void kernel_launch(void* const* d_in, const int* in_sizes, int n_in,
                              void* d_out, int out_size, void* d_ws,
                              size_t ws_size, hipStream_t stream) {
    const float* piece = (const float*)d_in[0];
    const int* widx = (const int*)d_in[1];
    const int* tidx = (const int*)d_in[2];
    const int* eidx = (const int*)d_in[3];
    const float* W0 = (const float*)d_in[4];
    const float* b0 = (const float*)d_in[5];
    const float* W1 = (const float*)d_in[6];
    const float* b1 = (const float*)d_in[7];
    float* out = (float*)d_out;

    float* ws = (float*)d_ws;
    float* word = ws;                               // NB*NW*ND f32 (dead after span_mean)
    float* trig = word + (size_t)NB * NW * ND;      // NB*NT*ND f32
    float* ent = trig + (size_t)NB * NT * ND;       // NB*NE*ND f32
    float* pre_t = ent + (size_t)NB * NE * ND;      // NB*NT*NH f32
    float* pre_e = pre_t + (size_t)NB * NT * NH;    // NB*NE*NH f32
    __bf16* W0pre = (__bf16*)word;                  // 5*32*IMGP bf16 (aliases dead word)
    __bf16* W0pair = W0pre + (size_t)5 * 32 * IMGP; // 2*32*IMGQ bf16

    hipMemsetAsync(d_out, 0, (size_t)out_size * sizeof(float), stream);

    word_mean_kernel<<<NB * NW, 256, 0, stream>>>(piece, widx, word);
    span_mean_kernel<<<NB * (NT + NE), 256, 0, stream>>>(word, tidx, eidx, trig, ent);
    // word is dead from here on; swizzle kernels overwrite it with images
    w0_swizzle_kernel<<<dim3(32, 5), 256, 0, stream>>>(W0, W0pre);
    w0_pair_kernel<<<dim3(32, 2, 4), 256, 0, stream>>>(W0, W0pair);
    pre_mfma_kernel<<<dim3(24, 10), 64, 0, stream>>>(trig, ent, W0pre, pre_t, pre_e);
    pair_mfma_kernel<<<dim3(16, 16, 2), 256, 0, stream>>>(
        trig, ent, W0pair, b0, pre_t, pre_e, W1, b1, out);
}